// Round 5
// baseline (249.302 us; speedup 1.0000x reference)
//
#include <hip/hip_runtime.h>
#include <hip/hip_bf16.h>
#include <hip/hip_fp16.h>

#define B_    64
#define HFS   56
#define CIN   96
#define NQ    785
#define NK    197
#define QW    28
#define KW    14
#define NTOT  3137    // 56*56+1
#define NQP   800     // q tokens padded to 16
#define NKP   208     // kv tokens padded to 16
#define VSTR  232     // vt row stride (shorts): 16B-aligned rows + 2-way-max banks
#define VR    96      // vt rows = v channels only (row sums now in-register)
#define KSCL  0.10206207261596575f   // 96^-0.5, folded into Wk
#define LOG2E 1.4426950408889634f    // exp(x) = exp2(x*log2e), folded into Wk/relc
#define KSCL2 (KSCL*LOG2E)

typedef __attribute__((ext_vector_type(8))) short short8;
typedef __attribute__((ext_vector_type(4))) short shortx4;
typedef __attribute__((ext_vector_type(4))) float floatx4;

__device__ __forceinline__ short f2s(float x) {
    __hip_bfloat16 h = __float2bfloat16(x);
    return *reinterpret_cast<short*>(&h);
}
__device__ __forceinline__ float s2f(short s) {
    __hip_bfloat16 h; *reinterpret_cast<short*>(&h) = s;
    return __bfloat162float(h);
}
__device__ __forceinline__ short8 ld8(const short* p) {
    return *reinterpret_cast<const short8*>(p);
}
__device__ __forceinline__ unsigned pkbf(float a, float b) {
    return (unsigned)(unsigned short)f2s(a) | ((unsigned)(unsigned short)f2s(b) << 16);
}
__device__ __forceinline__ unsigned pkhf(float a, float b) {
    __half2 h = __floats2half2_rn(a, b);
    return *reinterpret_cast<unsigned*>(&h);
}
__device__ __forceinline__ float hflo(unsigned w) {
    __half2 h = *reinterpret_cast<__half2*>(&w);
    return __half2float(__low2half(h));
}
__device__ __forceinline__ float hfhi(unsigned w) {
    __half2 h = *reinterpret_cast<__half2*>(&w);
    return __half2float(__high2half(h));
}

#define MFMA16(a,b,c) __builtin_amdgcn_mfma_f32_16x16x32_bf16((a),(b),(c),0,0,0)

// ---------------------------------------------------------------------------
// Kernel 0: prep = repack W^T (bf16; Wk pre-scaled by 96^-0.5*log2e), rel
// matrix (pre-scaled by log2e), vt pad-col zeros, conv-weight transposes.
// Total items: 66048 + 128*96*24 + 2592 = 363552
// ---------------------------------------------------------------------------
__global__ void prep_kernel(const float* __restrict__ Wq, const float* __restrict__ Wk,
                            const float* __restrict__ Wv, const float* __restrict__ relh,
                            const float* __restrict__ relw,
                            const float* __restrict__ pqw, const float* __restrict__ pkw,
                            const float* __restrict__ pvw,
                            short* __restrict__ WTq, short* __restrict__ WTk,
                            short* __restrict__ WTv, short* __restrict__ relc,
                            short* __restrict__ vt,
                            float* __restrict__ cwqT, float* __restrict__ cwkT,
                            float* __restrict__ cwvT)
{
    int i = blockIdx.x * 256 + threadIdx.x;
    if (i < 18432)      { int o = i/96, c = i%96;              WTq[o*96+c] = f2s(Wq[c*192+o]); }
    else if (i < 36864) { int j = i-18432; int o=j/96,c=j%96;  WTk[o*96+c] = f2s(Wk[c*192+o]*KSCL2); }
    else if (i < 55296) { int j = i-36864; int o=j/96,c=j%96;  WTv[o*96+c] = f2s(Wv[c*192+o]); }
    else if (i < 66048) {
        int j = i - 55296;  int r = j/96, c = j%96;            // 112*96
        float v = (r < 54) ? relh[r*96+c] : ((r < 108) ? relw[(r-54)*96+c] : 0.f);
        relc[r*96+c] = f2s(v*LOG2E);
    } else if (i < 360960) {
        int j2 = i - 66048;                                     // 128 bh * 96 rows * 24 pad cols
        int bh = j2 / 2304, r = j2 % 2304;
        int row = r / 24, tok = 208 + (r % 24);
        vt[(long)bh*(VR*VSTR) + row*VSTR + tok] = 0;
    } else if (i < 363552) {
        int j = i - 360960;                                     // 3 * 864
        int w = j / 864, r = j % 864;
        int c = r / 9, off = r % 9;
        const float* src = (w == 0) ? pqw : (w == 1) ? pkw : pvw;
        float*       dst = (w == 0) ? cwqT : (w == 1) ? cwkT : cwvT;
        dst[off*96 + c] = src[c*9 + off];
    }
}

// ---------------------------------------------------------------------------
// Kernel 1: depthwise 3x3 pool conv + LayerNorm -> bf16 pooled tokens.
// 4 tokens per wave: 16 lanes per token, 6 channels per lane (float2 x3).
// ---------------------------------------------------------------------------
__device__ __forceinline__ void red16_2(float& s, float& ss) {
    #pragma unroll
    for (int off = 8; off >= 1; off >>= 1) {
        s  += __shfl_xor(s,  off, 16);
        ss += __shfl_xor(ss, off, 16);
    }
}

__device__ __forceinline__ void ln6_store(const float* x, float m, float r,
    const float* __restrict__ g, const float* __restrict__ beta,
    int c0, short* __restrict__ outp)
{
    float2 g0 = *reinterpret_cast<const float2*>(g + c0);
    float2 g1 = *reinterpret_cast<const float2*>(g + c0 + 2);
    float2 g2 = *reinterpret_cast<const float2*>(g + c0 + 4);
    float2 b0 = *reinterpret_cast<const float2*>(beta + c0);
    float2 b1 = *reinterpret_cast<const float2*>(beta + c0 + 2);
    float2 b2 = *reinterpret_cast<const float2*>(beta + c0 + 4);
    unsigned o0 = pkbf((x[0]-m)*r*g0.x + b0.x, (x[1]-m)*r*g0.y + b0.y);
    unsigned o1 = pkbf((x[2]-m)*r*g1.x + b1.x, (x[3]-m)*r*g1.y + b1.y);
    unsigned o2 = pkbf((x[4]-m)*r*g2.x + b2.x, (x[5]-m)*r*g2.y + b2.y);
    *reinterpret_cast<unsigned*>(outp)     = o0;
    *reinterpret_cast<unsigned*>(outp + 2) = o1;
    *reinterpret_cast<unsigned*>(outp + 4) = o2;
}

__device__ __forceinline__ void zero6(short* __restrict__ outp) {
    *reinterpret_cast<unsigned*>(outp)     = 0u;
    *reinterpret_cast<unsigned*>(outp + 2) = 0u;
    *reinterpret_cast<unsigned*>(outp + 4) = 0u;
}

__global__ __launch_bounds__(256) void pool_ln_kernel(
    const float* __restrict__ hs,
    const float* __restrict__ cwqT, const float* __restrict__ cwkT, const float* __restrict__ cwvT,
    const float* __restrict__ gq, const float* __restrict__ betaq,
    const float* __restrict__ gk, const float* __restrict__ betak,
    const float* __restrict__ gv, const float* __restrict__ betav,
    short* __restrict__ pq, short* __restrict__ pk, short* __restrict__ pv)
{
    const int wid  = threadIdx.x >> 6;
    const int lane = threadIdx.x & 63;
    const int sub  = lane >> 4;               // token within wave
    const int li   = lane & 15;               // lane within token group
    const int c0   = li * 6;                  // channels c0..c0+5
    const int gid  = blockIdx.x * 4 + wid;    // 16128 waves total
    const int b    = gid / 252;
    const int slot = gid % 252;               // 200 q-slots + 52 kv-slots
    const long hb  = (long)b * NTOT * CIN;

    if (slot < 200) {                          // ---- q path (stride 2) ----
        int t = slot*4 + sub;
        short* outp = pq + ((long)b*NQP + t)*CIN + c0;
        if (t >= NQ) { zero6(outp); return; }
        float x[6];
        #pragma unroll
        for (int i = 0; i < 6; ++i) x[i] = 0.f;
        if (t == 0) {
            const float* hp = hs + hb + c0;
            float2 a0 = *reinterpret_cast<const float2*>(hp);
            float2 a1 = *reinterpret_cast<const float2*>(hp + 2);
            float2 a2 = *reinterpret_cast<const float2*>(hp + 4);
            x[0]=a0.x; x[1]=a0.y; x[2]=a1.x; x[3]=a1.y; x[4]=a2.x; x[5]=a2.y;
        } else {
            int j = t - 1, oy = j / QW, ox = j % QW;
            #pragma unroll
            for (int dy = 0; dy < 3; ++dy) {
                int iy = oy*2 - 1 + dy;
                #pragma unroll
                for (int dx = 0; dx < 3; ++dx) {
                    int ix = ox*2 - 1 + dx;
                    if (iy >= 0 && iy < HFS && ix >= 0 && ix < HFS) {
                        const float* hp = hs + hb + (long)(1 + iy*HFS + ix)*CIN + c0;
                        const float* wp = cwqT + (dy*3+dx)*96 + c0;
                        float2 h0 = *reinterpret_cast<const float2*>(hp);
                        float2 h1 = *reinterpret_cast<const float2*>(hp + 2);
                        float2 h2 = *reinterpret_cast<const float2*>(hp + 4);
                        float2 w0 = *reinterpret_cast<const float2*>(wp);
                        float2 w1 = *reinterpret_cast<const float2*>(wp + 2);
                        float2 w2 = *reinterpret_cast<const float2*>(wp + 4);
                        x[0] = fmaf(h0.x, w0.x, x[0]); x[1] = fmaf(h0.y, w0.y, x[1]);
                        x[2] = fmaf(h1.x, w1.x, x[2]); x[3] = fmaf(h1.y, w1.y, x[3]);
                        x[4] = fmaf(h2.x, w2.x, x[4]); x[5] = fmaf(h2.y, w2.y, x[5]);
                    }
                }
            }
        }
        float s  = (x[0]+x[1]) + (x[2]+x[3]) + (x[4]+x[5]);
        float ss = fmaf(x[0],x[0], fmaf(x[1],x[1], fmaf(x[2],x[2],
                   fmaf(x[3],x[3], fmaf(x[4],x[4], x[5]*x[5])))));
        red16_2(s, ss);
        float m   = s * (1.f/96.f);
        float var = ss * (1.f/96.f) - m*m;
        float r   = rsqrtf(var + 1e-5f);
        ln6_store(x, m, r, gq, betaq, c0, outp);
    } else {                                   // ---- k+v fused (stride 4) ----
        int tok = (slot - 200)*4 + sub;
        short* ok_ = pk + ((long)b*NKP + tok)*CIN + c0;
        short* ov_ = pv + ((long)b*NKP + tok)*CIN + c0;
        if (tok >= NK) { zero6(ok_); zero6(ov_); return; }
        float xk[6], xv[6];
        #pragma unroll
        for (int i = 0; i < 6; ++i) { xk[i] = 0.f; xv[i] = 0.f; }
        if (tok == 0) {
            const float* hp = hs + hb + c0;
            float2 a0 = *reinterpret_cast<const float2*>(hp);
            float2 a1 = *reinterpret_cast<const float2*>(hp + 2);
            float2 a2 = *reinterpret_cast<const float2*>(hp + 4);
            xk[0]=xv[0]=a0.x; xk[1]=xv[1]=a0.y; xk[2]=xv[2]=a1.x;
            xk[3]=xv[3]=a1.y; xk[4]=xv[4]=a2.x; xk[5]=xv[5]=a2.y;
        } else {
            int j = tok - 1, oy = j / KW, ox = j % KW;
            #pragma unroll
            for (int dy = 0; dy < 3; ++dy) {
                int iy = oy*4 - 1 + dy;
                #pragma unroll
                for (int dx = 0; dx < 3; ++dx) {
                    int ix = ox*4 - 1 + dx;
                    if (iy >= 0 && iy < HFS && ix >= 0 && ix < HFS) {
                        const float* hp = hs + hb + (long)(1 + iy*HFS + ix)*CIN + c0;
                        int wo = (dy*3+dx)*96 + c0;
                        float2 h0 = *reinterpret_cast<const float2*>(hp);
                        float2 h1 = *reinterpret_cast<const float2*>(hp + 2);
                        float2 h2 = *reinterpret_cast<const float2*>(hp + 4);
                        float2 k0 = *reinterpret_cast<const float2*>(cwkT + wo);
                        float2 k1 = *reinterpret_cast<const float2*>(cwkT + wo + 2);
                        float2 k2 = *reinterpret_cast<const float2*>(cwkT + wo + 4);
                        float2 v0 = *reinterpret_cast<const float2*>(cwvT + wo);
                        float2 v1 = *reinterpret_cast<const float2*>(cwvT + wo + 2);
                        float2 v2 = *reinterpret_cast<const float2*>(cwvT + wo + 4);
                        xk[0] = fmaf(h0.x, k0.x, xk[0]); xk[1] = fmaf(h0.y, k0.y, xk[1]);
                        xk[2] = fmaf(h1.x, k1.x, xk[2]); xk[3] = fmaf(h1.y, k1.y, xk[3]);
                        xk[4] = fmaf(h2.x, k2.x, xk[4]); xk[5] = fmaf(h2.y, k2.y, xk[5]);
                        xv[0] = fmaf(h0.x, v0.x, xv[0]); xv[1] = fmaf(h0.y, v0.y, xv[1]);
                        xv[2] = fmaf(h1.x, v1.x, xv[2]); xv[3] = fmaf(h1.y, v1.y, xv[3]);
                        xv[4] = fmaf(h2.x, v2.x, xv[4]); xv[5] = fmaf(h2.y, v2.y, xv[5]);
                    }
                }
            }
        }
        float sk  = (xk[0]+xk[1]) + (xk[2]+xk[3]) + (xk[4]+xk[5]);
        float ssk = fmaf(xk[0],xk[0], fmaf(xk[1],xk[1], fmaf(xk[2],xk[2],
                    fmaf(xk[3],xk[3], fmaf(xk[4],xk[4], xk[5]*xk[5])))));
        float sv  = (xv[0]+xv[1]) + (xv[2]+xv[3]) + (xv[4]+xv[5]);
        float ssv = fmaf(xv[0],xv[0], fmaf(xv[1],xv[1], fmaf(xv[2],xv[2],
                    fmaf(xv[3],xv[3], fmaf(xv[4],xv[4], xv[5]*xv[5])))));
        red16_2(sk, ssk);
        red16_2(sv, ssv);
        float mk = sk * (1.f/96.f), vark = ssk * (1.f/96.f) - mk*mk;
        float mv = sv * (1.f/96.f), varv = ssv * (1.f/96.f) - mv*mv;
        float rk = rsqrtf(vark + 1e-5f);
        float rv = rsqrtf(varv + 1e-5f);
        ln6_store(xk, mk, rk, gk, betak, c0, ok_);
        ln6_store(xv, mv, rv, gv, betav, c0, ov_);
    }
}

// ---------------------------------------------------------------------------
// Kernel 2: projections as MFMA GEMM. TWO 16-token tiles per wave; weight
// fragments double-buffered in registers. vt written at stride VSTR, VR rows.
// ---------------------------------------------------------------------------
__global__ __launch_bounds__(256) void proj_mfma_kernel(
    const short* __restrict__ pq, const short* __restrict__ pk, const short* __restrict__ pv,
    const short* __restrict__ WTq, const short* __restrict__ WTk, const short* __restrict__ WTv,
    const float* __restrict__ bq, const float* __restrict__ bk, const float* __restrict__ bv,
    short* __restrict__ qb, short* __restrict__ kb, short* __restrict__ vt)
{
    int wid  = threadIdx.x >> 6;
    int lane = threadIdx.x & 63;
    int quad = lane >> 4, col = lane & 15;
    int wt = blockIdx.x * 4 + wid;              // 2432 wave-pairs total

    if (wt < 2016) {                            // ---- q and k: swapped ----
        const short *A, *WT; const float* bias; short* outp;
        int ntokp, row0; float bsc;
        if (wt < 1600) { A = pq; WT = WTq; bias = bq; outp = qb; ntokp = NQP; row0 = wt*32; bsc = 1.f; }
        else           { A = pk; WT = WTk; bias = bk; outp = kb; ntokp = NKP; row0 = (wt-1600)*32; bsc = KSCL2; }

        short8 bt[2][3];
        #pragma unroll
        for (int ti = 0; ti < 2; ++ti)
            #pragma unroll
            for (int cc = 0; cc < 3; ++cc)
                bt[ti][cc] = ld8(A + (long)(row0 + ti*16 + col)*96 + cc*32 + quad*8);

        int bT[2], tokT[2];
        #pragma unroll
        for (int ti = 0; ti < 2; ++ti) {
            int r = row0 + ti*16;
            bT[ti] = r / ntokp;
            tokT[ti] = (r % ntokp) + col;
        }

        short8 af[2][3];
        #pragma unroll
        for (int cc = 0; cc < 3; ++cc)
            af[0][cc] = ld8(WT + col*96 + cc*32 + quad*8);

        #pragma unroll
        for (int nt = 0; nt < 12; ++nt) {
            if (nt < 11) {
                #pragma unroll
                for (int cc = 0; cc < 3; ++cc)
                    af[(nt+1)&1][cc] = ld8(WT + ((nt+1)*16 + col)*96 + cc*32 + quad*8);
            }
            int o0 = nt*16 + quad*4;            // 4 consecutive outputs
            float4 bo = *reinterpret_cast<const float4*>(bias + o0);
            int h  = (o0 >= 96) ? 1 : 0;
            int d0 = o0 - h*96;
            #pragma unroll
            for (int ti = 0; ti < 2; ++ti) {
                floatx4 acc = {0.f, 0.f, 0.f, 0.f};
                #pragma unroll
                for (int cc = 0; cc < 3; ++cc)
                    acc = MFMA16(af[nt&1][cc], bt[ti][cc], acc);
                shortx4 val;
                val.x = f2s(acc[0] + bo.x*bsc);
                val.y = f2s(acc[1] + bo.y*bsc);
                val.z = f2s(acc[2] + bo.z*bsc);
                val.w = f2s(acc[3] + bo.w*bsc);
                *reinterpret_cast<shortx4*>(outp + ((long)(bT[ti]*2 + h)*ntokp + tokT[ti])*96 + d0) = val;
            }
        }
    } else {                                    // ---- v: original orient ----
        int row0 = (wt - 2016) * 32;
        short8 at[2][3];
        #pragma unroll
        for (int ti = 0; ti < 2; ++ti)
            #pragma unroll
            for (int cc = 0; cc < 3; ++cc)
                at[ti][cc] = ld8(pv + (long)(row0 + ti*16 + col)*96 + cc*32 + quad*8);

        int bT[2], t0T[2];
        #pragma unroll
        for (int ti = 0; ti < 2; ++ti) {
            int r = row0 + ti*16;
            bT[ti] = r / NKP;
            t0T[ti] = (r % NKP) + quad*4;       // 4 consecutive tokens
        }

        short8 bf[2][3];
        #pragma unroll
        for (int cc = 0; cc < 3; ++cc)
            bf[0][cc] = ld8(WTv + col*96 + cc*32 + quad*8);

        #pragma unroll
        for (int nt = 0; nt < 12; ++nt) {
            if (nt < 11) {
                #pragma unroll
                for (int cc = 0; cc < 3; ++cc)
                    bf[(nt+1)&1][cc] = ld8(WTv + ((nt+1)*16 + col)*96 + cc*32 + quad*8);
            }
            int o = nt*16 + col;
            int h = (o >= 96) ? 1 : 0;
            int d = o - h*96;
            float bo = bv[o];
            #pragma unroll
            for (int ti = 0; ti < 2; ++ti) {
                floatx4 acc = {0.f, 0.f, 0.f, 0.f};
                #pragma unroll
                for (int cc = 0; cc < 3; ++cc)
                    acc = MFMA16(at[ti][cc], bf[nt&1][cc], acc);
                shortx4 val;
                val.x = (t0T[ti]+0 < NK) ? f2s(acc[0] + bo) : (short)0;
                val.y = (t0T[ti]+1 < NK) ? f2s(acc[1] + bo) : (short)0;
                val.z = (t0T[ti]+2 < NK) ? f2s(acc[2] + bo) : (short)0;
                val.w = (t0T[ti]+3 < NK) ? f2s(acc[3] + bo) : (short)0;
                *reinterpret_cast<shortx4*>(vt + ((long)(bT[ti]*2 + h)*VR + d)*VSTR + t0T[ti]) = val;
            }
        }
    }
}

// ---------------------------------------------------------------------------
// Kernel 3: MFMA attention. 4-wave blocks, 7 blocks per bh (896 total).
// All 4 waves cooperatively stage this bh's V panel (96x232 bf16, 44 KB)
// into LDS ONCE; PV then reads V from LDS (12cy) instead of L2/L3 (200-600cy).
// Each wave: 2 q-tiles processed SEQUENTIALLY (single 7.4 KB P buffer/wave),
// so block LDS = 74.7 KB -> 2 blocks/CU residency. K streamed with dist-2
// register ring. Row-sums in registers (masked exp + width-16 shfl reduce).
// One barrier, placed after S(tile0) so staging latency hides under E+S.
// ---------------------------------------------------------------------------
__global__ __launch_bounds__(256, 2) void attn_kernel(
    const short* __restrict__ qb, const short* __restrict__ kb,
    const short* __restrict__ vt, const short* __restrict__ relc,
    float* __restrict__ out)
{
    __shared__ __align__(16) short Vlds[22528];        // 96x232 + slack (45056 B)
    __shared__ __align__(16) short Plds[4][16][232];   // per-wave E/P (29696 B)

    int tid  = threadIdx.x;
    int wid  = tid >> 6;
    int lane = tid & 63;
    int quad = lane >> 4, col = lane & 15;

    int bid = blockIdx.x;                      // 896 = 8 XCD x 112
    int xcd = bid & 7, idx = bid >> 3;         // idx 0..111
    int bh  = xcd*16 + idx/7;                  // 16 contiguous bh per XCD
    int j   = idx % 7;
    int unit = j*4 + wid;                      // 0..27 (25 valid)
    bool active = (unit < 25);
    int u  = active ? unit : 24;               // idle waves duplicate unit 24
    int q0 = u * 32;

    // ---- cooperative V stage: 44 x 1024B chunks, 11 per wave ----
    const short* vtg = vt + (long)bh * (VR*VSTR);
    {
        short8 tmp[11];
        #pragma unroll
        for (int t = 0; t < 11; ++t)
            tmp[t] = ld8(vtg + (wid + t*4)*512 + lane*8);
        #pragma unroll
        for (int t = 0; t < 11; ++t)
            *reinterpret_cast<short8*>(&Vlds[(wid + t*4)*512 + lane*8]) = tmp[t];
    }

    const short* kbase = kb + (long)bh*NKP*96;
    int b = bh >> 1, h = bh & 1;

    #pragma unroll
    for (int ti = 0; ti < 2; ++ti) {
        // Q A-fragments for this tile
        const short* qrow = qb + ((long)bh*NQP + q0 + ti*16)*96;
        short8 aq[3];
        #pragma unroll
        for (int c = 0; c < 3; ++c)
            aq[c] = ld8(qrow + col*96 + c*32 + quad*8);

        // E = Q Rel^T (rel dist-1 double buffer) -> Plds cols 0..111
        short8 rf[2][3];
        #pragma unroll
        for (int c = 0; c < 3; ++c)
            rf[0][c] = ld8(relc + col*96 + c*32 + quad*8);
        #pragma unroll
        for (int rt = 0; rt < 7; ++rt) {
            if (rt < 6) {
                #pragma unroll
                for (int c = 0; c < 3; ++c)
                    rf[(rt+1)&1][c] = ld8(relc + ((rt+1)*16 + col)*96 + c*32 + quad*8);
            }
            floatx4 acc = {0.f, 0.f, 0.f, 0.f};
            #pragma unroll
            for (int c = 0; c < 3; ++c)
                acc = MFMA16(aq[c], rf[rt&1][c], acc);
            #pragma unroll
            for (int reg = 0; reg < 4; ++reg)
                Plds[wid][quad*4 + reg][rt*16 + col] = f2s(acc[reg]);
        }

        // per-row q spatial coords
        int qyo[4], qxo[4];
        #pragma unroll
        for (int reg = 0; reg < 4; ++reg) {
            int qq = q0 + ti*16 + quad*4 + reg;
            int jj = (qq > 0) ? (qq - 1) : 0;
            qyo[reg] = jj / QW;
            qxo[reg] = jj % QW;
        }

        // hoisted rel-bias gather: 13 kt x 4 rows -> 26 packed-f16 regs
        unsigned bpk[13][2];
        #pragma unroll
        for (int kt = 0; kt < 13; ++kt) {
            int k  = kt*16 + col;
            int kk = (k > 0) ? (k - 1) : 0;
            int ky = kk / 14;  ky = (ky < 13) ? ky : 13;
            int kx = kk - 14*ky;
            int oh  = 26 - 2*ky;
            int ow2 = 26 - 2*kx;
            float bs[4];
            #pragma unroll
            for (int reg = 0; reg < 4; ++reg) {
                const short* er = &Plds[wid][quad*4 + reg][0];
                float bias = s2f(er[qyo[reg] + oh]) + s2f(er[54 + qxo[reg] + ow2]);
                if (kt == 0) bias = (col == 0) ? 0.f : bias;                        // CLS col
                if (q0 == 0 && ti == 0 && reg == 0) bias = (quad == 0) ? 0.f : bias; // CLS row
                bs[reg] = bias;
            }
            bpk[kt][0] = pkhf(bs[0], bs[1]);
            bpk[kt][1] = pkhf(bs[2], bs[3]);
        }

        // S = exp2(Q K^T + bias) -> P (overwrites E); K dist-2 register ring;
        // pad-k masked to 0; row-sums accumulated in registers (f32).
        float rsum[4] = {0.f, 0.f, 0.f, 0.f};
        short8 kf[3][3];
        #pragma unroll
        for (int c = 0; c < 3; ++c)
            kf[0][c] = ld8(kbase + col*96 + c*32 + quad*8);
        #pragma unroll
        for (int c = 0; c < 3; ++c)
            kf[1][c] = ld8(kbase + (16 + col)*96 + c*32 + quad*8);
        #pragma unroll
        for (int kt = 0; kt < 13; ++kt) {
            if (kt < 11) {
                #pragma unroll
                for (int c = 0; c < 3; ++c)
                    kf[(kt+2)%3][c] = ld8(kbase + ((kt+2)*16 + col)*96 + c*32 + quad*8);
            }
            __builtin_amdgcn_s_setprio(1);
            floatx4 acc = {0.f, 0.f, 0.f, 0.f};
            #pragma unroll
            for (int c = 0; c < 3; ++c)
                acc = MFMA16(aq[c], kf[kt%3][c], acc);
            __builtin_amdgcn_s_setprio(0);
            int k = kt*16 + col;
            unsigned w0 = bpk[kt][0], w1 = bpk[kt][1];
            float e0 = __builtin_amdgcn_exp2f(acc[0] + hflo(w0));
            float e1 = __builtin_amdgcn_exp2f(acc[1] + hfhi(w0));
            float e2 = __builtin_amdgcn_exp2f(acc[2] + hflo(w1));
            float e3 = __builtin_amdgcn_exp2f(acc[3] + hfhi(w1));
            if (k >= NK) { e0 = 0.f; e1 = 0.f; e2 = 0.f; e3 = 0.f; }
            Plds[wid][quad*4 + 0][k] = f2s(e0);
            Plds[wid][quad*4 + 1][k] = f2s(e1);
            Plds[wid][quad*4 + 2][k] = f2s(e2);
            Plds[wid][quad*4 + 3][k] = f2s(e3);
            rsum[0] += e0; rsum[1] += e1; rsum[2] += e2; rsum[3] += e3;
        }
        #pragma unroll
        for (int reg = 0; reg < 4; ++reg)      // zero PV pad cols 208..223
            Plds[wid][quad*4 + reg][208 + col] = 0;

        // row sums: reduce across the 16 cols of this quad
        float inv[4];
        #pragma unroll
        for (int reg = 0; reg < 4; ++reg) {
            float s = rsum[reg];
            s += __shfl_xor(s, 1, 16);
            s += __shfl_xor(s, 2, 16);
            s += __shfl_xor(s, 4, 16);
            s += __shfl_xor(s, 8, 16);
            inv[reg] = 1.0f / s;
        }

        if (ti == 0) __syncthreads();          // V staging complete (uniform)

        // O = P V from LDS (6 channel n-tiles x 7 K-chunks)
        floatx4 o[6];
        #pragma unroll
        for (int nt = 0; nt < 6; ++nt) o[nt] = floatx4{0.f, 0.f, 0.f, 0.f};
        #pragma unroll
        for (int c = 0; c < 7; ++c) {
            short8 pA = ld8(&Plds[wid][col][c*32 + quad*8]);
            __builtin_amdgcn_s_setprio(1);
            #pragma unroll
            for (int nt = 0; nt < 6; ++nt) {
                short8 vb = ld8(&Vlds[(nt*16 + col)*VSTR + c*32 + quad*8]);
                o[nt] = MFMA16(pA, vb, o[nt]);
            }
            __builtin_amdgcn_s_setprio(0);
        }

        // epilogue: normalize, +residual, store
        #pragma unroll
        for (int nt = 0; nt < 6; ++nt) {
            int ch = nt*16 + col;
            #pragma unroll
            for (int reg = 0; reg < 4; ++reg) {
                int q = q0 + ti*16 + quad*4 + reg;
                if (active && q < NQ) {
                    float val = o[nt][reg] * inv[reg];
                    if (q > 0) val += s2f(qb[((long)bh*NQP + q)*96 + ch]);
                    out[((long)b*NQ + q)*192 + h*96 + ch] = val;
                }
            }
        }
    }
}

// ---------------------------------------------------------------------------
extern "C" void kernel_launch(void* const* d_in, const int* in_sizes, int n_in,
                              void* d_out, int out_size, void* d_ws, size_t ws_size,
                              hipStream_t stream)
{
    const float* hs    = (const float*)d_in[0];
    const float* Wq    = (const float*)d_in[1];
    const float* bq    = (const float*)d_in[2];
    const float* Wk    = (const float*)d_in[3];
    const float* bk    = (const float*)d_in[4];
    const float* Wv    = (const float*)d_in[5];
    const float* bv    = (const float*)d_in[6];
    const float* pqw   = (const float*)d_in[7];
    const float* pkw   = (const float*)d_in[8];
    const float* pvw   = (const float*)d_in[9];
    const float* gq    = (const float*)d_in[10];
    const float* betaq = (const float*)d_in[11];
    const float* gk    = (const float*)d_in[12];
    const float* betak = (const float*)d_in[13];
    const float* gv    = (const float*)d_in[14];
    const float* betav = (const float*)d_in[15];
    const float* relh  = (const float*)d_in[16];
    const float* relw  = (const float*)d_in[17];
    float* out = (float*)d_out;

    // workspace carve (bf16 as short) — ~45 MB
    short* pq   = (short*)d_ws;                  // [64][800][96]
    short* pk   = pq  + (long)B_*NQP*CIN;        // [64][208][96]
    short* pv   = pk  + (long)B_*NKP*CIN;        // [64][208][96]
    short* qb   = pv  + (long)B_*NKP*CIN;        // [128][800][96]
    short* kb   = qb  + (long)128*NQP*96;        // [128][208][96]
    short* vt   = kb  + (long)128*NKP*96;        // [128][96][232]
    short* WTq  = vt  + (long)128*VR*VSTR;       // [192][96]
    short* WTk  = WTq + 192*96;
    short* WTv  = WTk + 192*96;
    short* relc = WTv + 192*96;                  // [112][96]
    float* cwqT = (float*)(relc + 112*96);       // [9][96] fp32
    float* cwkT = cwqT + 9*96;
    float* cwvT = cwkT + 9*96;

    prep_kernel<<<1421, 256, 0, stream>>>(Wq, Wk, Wv, relh, relw,
                                          pqw, pkw, pvw,
                                          WTq, WTk, WTv, relc, vt,
                                          cwqT, cwkT, cwvT);

    pool_ln_kernel<<<(B_*1008)/16, 256, 0, stream>>>(
        hs, cwqT, cwkT, cwvT, gq, betaq, gk, betak, gv, betav, pq, pk, pv);

    proj_mfma_kernel<<<2432/4, 256, 0, stream>>>(
        pq, pk, pv, WTq, WTk, WTv, bq, bk, bv, qb, kb, vt);

    attn_kernel<<<896, 256, 0, stream>>>(qb, kb, vt, relc, out);
}

// Round 6
// 240.534 us; speedup vs baseline: 1.0365x; 1.0365x over previous
//
#include <hip/hip_runtime.h>
#include <hip/hip_bf16.h>
#include <hip/hip_fp16.h>

#define B_    64
#define HFS   56
#define CIN   96
#define NQ    785
#define NK    197
#define QW    28
#define KW    14
#define NTOT  3137    // 56*56+1
#define NQP   800     // q tokens padded to 16
#define NKP   208     // kv tokens padded to 16
#define NKPV  224     // PV K-dim padded to 32
#define VROWS 112     // 96 v channels + ones row + 15 zero rows
#define KSCL  0.10206207261596575f   // 96^-0.5, folded into Wk
#define LOG2E 1.4426950408889634f    // exp(x) = exp2(x*log2e), folded into Wk/relc
#define KSCL2 (KSCL*LOG2E)

typedef __attribute__((ext_vector_type(8))) short short8;
typedef __attribute__((ext_vector_type(4))) short shortx4;
typedef __attribute__((ext_vector_type(4))) float floatx4;

__device__ __forceinline__ short f2s(float x) {
    __hip_bfloat16 h = __float2bfloat16(x);
    return *reinterpret_cast<short*>(&h);
}
__device__ __forceinline__ float s2f(short s) {
    __hip_bfloat16 h; *reinterpret_cast<short*>(&h) = s;
    return __bfloat162float(h);
}
__device__ __forceinline__ short8 ld8(const short* p) {
    return *reinterpret_cast<const short8*>(p);
}
__device__ __forceinline__ unsigned pkbf(float a, float b) {
    return (unsigned)(unsigned short)f2s(a) | ((unsigned)(unsigned short)f2s(b) << 16);
}
__device__ __forceinline__ unsigned pkhf(float a, float b) {
    __half2 h = __floats2half2_rn(a, b);
    return *reinterpret_cast<unsigned*>(&h);
}
__device__ __forceinline__ float hflo(unsigned w) {
    __half2 h = *reinterpret_cast<__half2*>(&w);
    return __half2float(__low2half(h));
}
__device__ __forceinline__ float hfhi(unsigned w) {
    __half2 h = *reinterpret_cast<__half2*>(&w);
    return __half2float(__high2half(h));
}

#define MFMA16(a,b,c) __builtin_amdgcn_mfma_f32_16x16x32_bf16((a),(b),(c),0,0,0)

// ---------------------------------------------------------------------------
// Kernel 0: prep = repack W^T (bf16; Wk pre-scaled by 96^-0.5*log2e), rel
// matrix (pre-scaled by log2e), vt pad init, conv-weight transposes.
// ---------------------------------------------------------------------------
__global__ void prep_kernel(const float* __restrict__ Wq, const float* __restrict__ Wk,
                            const float* __restrict__ Wv, const float* __restrict__ relh,
                            const float* __restrict__ relw,
                            const float* __restrict__ pqw, const float* __restrict__ pkw,
                            const float* __restrict__ pvw,
                            short* __restrict__ WTq, short* __restrict__ WTk,
                            short* __restrict__ WTv, short* __restrict__ relc,
                            short* __restrict__ vt,
                            float* __restrict__ cwqT, float* __restrict__ cwkT,
                            float* __restrict__ cwvT)
{
    int i = blockIdx.x * 256 + threadIdx.x;           // 724000 total
    if (i < 18432)      { int o = i/96, c = i%96;              WTq[o*96+c] = f2s(Wq[c*192+o]); }
    else if (i < 36864) { int j = i-18432; int o=j/96,c=j%96;  WTk[o*96+c] = f2s(Wk[c*192+o]*KSCL2); }
    else if (i < 55296) { int j = i-36864; int o=j/96,c=j%96;  WTv[o*96+c] = f2s(Wv[c*192+o]); }
    else if (i < 66048) {
        int j = i - 55296;  int r = j/96, c = j%96;            // 112*96
        float v = (r < 54) ? relh[r*96+c] : ((r < 108) ? relw[(r-54)*96+c] : 0.f);
        relc[r*96+c] = f2s(v*LOG2E);
    } else if (i < 721408) {
        int j2 = i - 66048;                                     // 128 * 5120
        int bh = j2 / 5120, r = j2 % 5120;
        int row, tok; short val;
        if (r < 3584) { row = 96 + r/224; tok = r%224;
                        val = (row == 96 && tok < NK) ? (short)0x3F80 : (short)0; }
        else          { int rr = r-3584; row = rr/16; tok = 208 + (rr%16); val = 0; }
        vt[((long)bh*VROWS + row)*NKPV + tok] = val;
    } else if (i < 724000) {
        int j = i - 721408;                                     // 3 * 864
        int w = j / 864, r = j % 864;
        int c = r / 9, off = r % 9;
        const float* src = (w == 0) ? pqw : (w == 1) ? pkw : pvw;
        float*       dst = (w == 0) ? cwqT : (w == 1) ? cwkT : cwvT;
        dst[off*96 + c] = src[c*9 + off];
    }
}

// ---------------------------------------------------------------------------
// Kernel 1: depthwise 3x3 pool conv + LayerNorm -> bf16 pooled tokens.
// 4 tokens per wave: 16 lanes per token, 6 channels per lane.
// NEW: all 9 taps' h-values prefetched into registers in one burst (27
// independent 8B loads in flight) before the fma pass; k+v share the h regs.
// ---------------------------------------------------------------------------
__device__ __forceinline__ void red16_2(float& s, float& ss) {
    #pragma unroll
    for (int off = 8; off >= 1; off >>= 1) {
        s  += __shfl_xor(s,  off, 16);
        ss += __shfl_xor(ss, off, 16);
    }
}

__device__ __forceinline__ void ln6_store(const float* x, float m, float r,
    const float* __restrict__ g, const float* __restrict__ beta,
    int c0, short* __restrict__ outp)
{
    float2 g0 = *reinterpret_cast<const float2*>(g + c0);
    float2 g1 = *reinterpret_cast<const float2*>(g + c0 + 2);
    float2 g2 = *reinterpret_cast<const float2*>(g + c0 + 4);
    float2 b0 = *reinterpret_cast<const float2*>(beta + c0);
    float2 b1 = *reinterpret_cast<const float2*>(beta + c0 + 2);
    float2 b2 = *reinterpret_cast<const float2*>(beta + c0 + 4);
    unsigned o0 = pkbf((x[0]-m)*r*g0.x + b0.x, (x[1]-m)*r*g0.y + b0.y);
    unsigned o1 = pkbf((x[2]-m)*r*g1.x + b1.x, (x[3]-m)*r*g1.y + b1.y);
    unsigned o2 = pkbf((x[4]-m)*r*g2.x + b2.x, (x[5]-m)*r*g2.y + b2.y);
    *reinterpret_cast<unsigned*>(outp)     = o0;
    *reinterpret_cast<unsigned*>(outp + 2) = o1;
    *reinterpret_cast<unsigned*>(outp + 4) = o2;
}

__device__ __forceinline__ void zero6(short* __restrict__ outp) {
    *reinterpret_cast<unsigned*>(outp)     = 0u;
    *reinterpret_cast<unsigned*>(outp + 2) = 0u;
    *reinterpret_cast<unsigned*>(outp + 4) = 0u;
}

__global__ __launch_bounds__(256) void pool_ln_kernel(
    const float* __restrict__ hs,
    const float* __restrict__ cwqT, const float* __restrict__ cwkT, const float* __restrict__ cwvT,
    const float* __restrict__ gq, const float* __restrict__ betaq,
    const float* __restrict__ gk, const float* __restrict__ betak,
    const float* __restrict__ gv, const float* __restrict__ betav,
    short* __restrict__ pq, short* __restrict__ pk, short* __restrict__ pv)
{
    const int wid  = threadIdx.x >> 6;
    const int lane = threadIdx.x & 63;
    const int sub  = lane >> 4;               // token within wave
    const int li   = lane & 15;               // lane within token group
    const int c0   = li * 6;                  // channels c0..c0+5
    const int gid  = blockIdx.x * 4 + wid;    // 16128 waves total
    const int b    = gid / 252;
    const int slot = gid % 252;               // 200 q-slots + 52 kv-slots
    const long hb  = (long)b * NTOT * CIN;

    if (slot < 200) {                          // ---- q path (stride 2) ----
        int t = slot*4 + sub;
        short* outp = pq + ((long)b*NQP + t)*CIN + c0;
        if (t >= NQ) { zero6(outp); return; }
        float x[6];
        #pragma unroll
        for (int i = 0; i < 6; ++i) x[i] = 0.f;
        if (t == 0) {
            const float* hp = hs + hb + c0;
            float2 a0 = *reinterpret_cast<const float2*>(hp);
            float2 a1 = *reinterpret_cast<const float2*>(hp + 2);
            float2 a2 = *reinterpret_cast<const float2*>(hp + 4);
            x[0]=a0.x; x[1]=a0.y; x[2]=a1.x; x[3]=a1.y; x[4]=a2.x; x[5]=a2.y;
        } else {
            int j = t - 1, oy = j / QW, ox = j % QW;
            float2 hbuf[9][3];
            #pragma unroll
            for (int tap = 0; tap < 9; ++tap) {
                int dy = tap / 3, dx = tap % 3;
                int iy = oy*2 - 1 + dy;
                int ix = ox*2 - 1 + dx;
                if (iy >= 0 && iy < HFS && ix >= 0 && ix < HFS) {
                    const float* hp = hs + hb + (long)(1 + iy*HFS + ix)*CIN + c0;
                    hbuf[tap][0] = *reinterpret_cast<const float2*>(hp);
                    hbuf[tap][1] = *reinterpret_cast<const float2*>(hp + 2);
                    hbuf[tap][2] = *reinterpret_cast<const float2*>(hp + 4);
                } else {
                    hbuf[tap][0] = float2{0.f, 0.f};
                    hbuf[tap][1] = float2{0.f, 0.f};
                    hbuf[tap][2] = float2{0.f, 0.f};
                }
            }
            #pragma unroll
            for (int tap = 0; tap < 9; ++tap) {
                const float* wp = cwqT + tap*96 + c0;
                float2 w0 = *reinterpret_cast<const float2*>(wp);
                float2 w1 = *reinterpret_cast<const float2*>(wp + 2);
                float2 w2 = *reinterpret_cast<const float2*>(wp + 4);
                x[0] = fmaf(hbuf[tap][0].x, w0.x, x[0]); x[1] = fmaf(hbuf[tap][0].y, w0.y, x[1]);
                x[2] = fmaf(hbuf[tap][1].x, w1.x, x[2]); x[3] = fmaf(hbuf[tap][1].y, w1.y, x[3]);
                x[4] = fmaf(hbuf[tap][2].x, w2.x, x[4]); x[5] = fmaf(hbuf[tap][2].y, w2.y, x[5]);
            }
        }
        float s  = (x[0]+x[1]) + (x[2]+x[3]) + (x[4]+x[5]);
        float ss = fmaf(x[0],x[0], fmaf(x[1],x[1], fmaf(x[2],x[2],
                   fmaf(x[3],x[3], fmaf(x[4],x[4], x[5]*x[5])))));
        red16_2(s, ss);
        float m   = s * (1.f/96.f);
        float var = ss * (1.f/96.f) - m*m;
        float r   = rsqrtf(var + 1e-5f);
        ln6_store(x, m, r, gq, betaq, c0, outp);
    } else {                                   // ---- k+v fused (stride 4) ----
        int tok = (slot - 200)*4 + sub;
        short* ok_ = pk + ((long)b*NKP + tok)*CIN + c0;
        short* ov_ = pv + ((long)b*NKP + tok)*CIN + c0;
        if (tok >= NK) { zero6(ok_); zero6(ov_); return; }
        float xk[6], xv[6];
        #pragma unroll
        for (int i = 0; i < 6; ++i) { xk[i] = 0.f; xv[i] = 0.f; }
        if (tok == 0) {
            const float* hp = hs + hb + c0;
            float2 a0 = *reinterpret_cast<const float2*>(hp);
            float2 a1 = *reinterpret_cast<const float2*>(hp + 2);
            float2 a2 = *reinterpret_cast<const float2*>(hp + 4);
            xk[0]=xv[0]=a0.x; xk[1]=xv[1]=a0.y; xk[2]=xv[2]=a1.x;
            xk[3]=xv[3]=a1.y; xk[4]=xv[4]=a2.x; xk[5]=xv[5]=a2.y;
        } else {
            int j = tok - 1, oy = j / KW, ox = j % KW;
            float2 hbuf[9][3];
            #pragma unroll
            for (int tap = 0; tap < 9; ++tap) {
                int dy = tap / 3, dx = tap % 3;
                int iy = oy*4 - 1 + dy;
                int ix = ox*4 - 1 + dx;
                if (iy >= 0 && iy < HFS && ix >= 0 && ix < HFS) {
                    const float* hp = hs + hb + (long)(1 + iy*HFS + ix)*CIN + c0;
                    hbuf[tap][0] = *reinterpret_cast<const float2*>(hp);
                    hbuf[tap][1] = *reinterpret_cast<const float2*>(hp + 2);
                    hbuf[tap][2] = *reinterpret_cast<const float2*>(hp + 4);
                } else {
                    hbuf[tap][0] = float2{0.f, 0.f};
                    hbuf[tap][1] = float2{0.f, 0.f};
                    hbuf[tap][2] = float2{0.f, 0.f};
                }
            }
            #pragma unroll
            for (int tap = 0; tap < 9; ++tap) {
                int wo = tap*96 + c0;
                float2 k0 = *reinterpret_cast<const float2*>(cwkT + wo);
                float2 k1 = *reinterpret_cast<const float2*>(cwkT + wo + 2);
                float2 k2 = *reinterpret_cast<const float2*>(cwkT + wo + 4);
                float2 v0 = *reinterpret_cast<const float2*>(cwvT + wo);
                float2 v1 = *reinterpret_cast<const float2*>(cwvT + wo + 2);
                float2 v2 = *reinterpret_cast<const float2*>(cwvT + wo + 4);
                xk[0] = fmaf(hbuf[tap][0].x, k0.x, xk[0]); xk[1] = fmaf(hbuf[tap][0].y, k0.y, xk[1]);
                xk[2] = fmaf(hbuf[tap][1].x, k1.x, xk[2]); xk[3] = fmaf(hbuf[tap][1].y, k1.y, xk[3]);
                xk[4] = fmaf(hbuf[tap][2].x, k2.x, xk[4]); xk[5] = fmaf(hbuf[tap][2].y, k2.y, xk[5]);
                xv[0] = fmaf(hbuf[tap][0].x, v0.x, xv[0]); xv[1] = fmaf(hbuf[tap][0].y, v0.y, xv[1]);
                xv[2] = fmaf(hbuf[tap][1].x, v1.x, xv[2]); xv[3] = fmaf(hbuf[tap][1].y, v1.y, xv[3]);
                xv[4] = fmaf(hbuf[tap][2].x, v2.x, xv[4]); xv[5] = fmaf(hbuf[tap][2].y, v2.y, xv[5]);
            }
        }
        float sk  = (xk[0]+xk[1]) + (xk[2]+xk[3]) + (xk[4]+xk[5]);
        float ssk = fmaf(xk[0],xk[0], fmaf(xk[1],xk[1], fmaf(xk[2],xk[2],
                    fmaf(xk[3],xk[3], fmaf(xk[4],xk[4], xk[5]*xk[5])))));
        float sv  = (xv[0]+xv[1]) + (xv[2]+xv[3]) + (xv[4]+xv[5]);
        float ssv = fmaf(xv[0],xv[0], fmaf(xv[1],xv[1], fmaf(xv[2],xv[2],
                    fmaf(xv[3],xv[3], fmaf(xv[4],xv[4], xv[5]*xv[5])))));
        red16_2(sk, ssk);
        red16_2(sv, ssv);
        float mk = sk * (1.f/96.f), vark = ssk * (1.f/96.f) - mk*mk;
        float mv = sv * (1.f/96.f), varv = ssv * (1.f/96.f) - mv*mv;
        float rk = rsqrtf(vark + 1e-5f);
        float rv = rsqrtf(varv + 1e-5f);
        ln6_store(xk, mk, rk, gk, betak, c0, ok_);
        ln6_store(xv, mv, rv, gv, betav, c0, ov_);
    }
}

// ---------------------------------------------------------------------------
// Kernel 2: projections as MFMA GEMM. TWO 16-token tiles per wave; weight
// fragments double-buffered in registers (dist-1 prefetch).
// ---------------------------------------------------------------------------
__global__ __launch_bounds__(256) void proj_mfma_kernel(
    const short* __restrict__ pq, const short* __restrict__ pk, const short* __restrict__ pv,
    const short* __restrict__ WTq, const short* __restrict__ WTk, const short* __restrict__ WTv,
    const float* __restrict__ bq, const float* __restrict__ bk, const float* __restrict__ bv,
    short* __restrict__ qb, short* __restrict__ kb, short* __restrict__ vt)
{
    int wid  = threadIdx.x >> 6;
    int lane = threadIdx.x & 63;
    int quad = lane >> 4, col = lane & 15;
    int wt = blockIdx.x * 4 + wid;              // 2432 wave-pairs total

    if (wt < 2016) {                            // ---- q and k: swapped ----
        const short *A, *WT; const float* bias; short* outp;
        int ntokp, row0; float bsc;
        if (wt < 1600) { A = pq; WT = WTq; bias = bq; outp = qb; ntokp = NQP; row0 = wt*32; bsc = 1.f; }
        else           { A = pk; WT = WTk; bias = bk; outp = kb; ntokp = NKP; row0 = (wt-1600)*32; bsc = KSCL2; }

        short8 bt[2][3];
        #pragma unroll
        for (int ti = 0; ti < 2; ++ti)
            #pragma unroll
            for (int cc = 0; cc < 3; ++cc)
                bt[ti][cc] = ld8(A + (long)(row0 + ti*16 + col)*96 + cc*32 + quad*8);

        int bT[2], tokT[2];
        #pragma unroll
        for (int ti = 0; ti < 2; ++ti) {
            int r = row0 + ti*16;
            bT[ti] = r / ntokp;
            tokT[ti] = (r % ntokp) + col;
        }

        short8 af[2][3];
        #pragma unroll
        for (int cc = 0; cc < 3; ++cc)
            af[0][cc] = ld8(WT + col*96 + cc*32 + quad*8);

        #pragma unroll
        for (int nt = 0; nt < 12; ++nt) {
            if (nt < 11) {
                #pragma unroll
                for (int cc = 0; cc < 3; ++cc)
                    af[(nt+1)&1][cc] = ld8(WT + ((nt+1)*16 + col)*96 + cc*32 + quad*8);
            }
            int o0 = nt*16 + quad*4;            // 4 consecutive outputs
            float4 bo = *reinterpret_cast<const float4*>(bias + o0);
            int h  = (o0 >= 96) ? 1 : 0;
            int d0 = o0 - h*96;
            #pragma unroll
            for (int ti = 0; ti < 2; ++ti) {
                floatx4 acc = {0.f, 0.f, 0.f, 0.f};
                #pragma unroll
                for (int cc = 0; cc < 3; ++cc)
                    acc = MFMA16(af[nt&1][cc], bt[ti][cc], acc);
                shortx4 val;
                val.x = f2s(acc[0] + bo.x*bsc);
                val.y = f2s(acc[1] + bo.y*bsc);
                val.z = f2s(acc[2] + bo.z*bsc);
                val.w = f2s(acc[3] + bo.w*bsc);
                *reinterpret_cast<shortx4*>(outp + ((long)(bT[ti]*2 + h)*ntokp + tokT[ti])*96 + d0) = val;
            }
        }
    } else {                                    // ---- v: original orient ----
        int row0 = (wt - 2016) * 32;
        short8 at[2][3];
        #pragma unroll
        for (int ti = 0; ti < 2; ++ti)
            #pragma unroll
            for (int cc = 0; cc < 3; ++cc)
                at[ti][cc] = ld8(pv + (long)(row0 + ti*16 + col)*96 + cc*32 + quad*8);

        int bT[2], t0T[2];
        #pragma unroll
        for (int ti = 0; ti < 2; ++ti) {
            int r = row0 + ti*16;
            bT[ti] = r / NKP;
            t0T[ti] = (r % NKP) + quad*4;       // 4 consecutive tokens
        }

        short8 bf[2][3];
        #pragma unroll
        for (int cc = 0; cc < 3; ++cc)
            bf[0][cc] = ld8(WTv + col*96 + cc*32 + quad*8);

        #pragma unroll
        for (int nt = 0; nt < 12; ++nt) {
            if (nt < 11) {
                #pragma unroll
                for (int cc = 0; cc < 3; ++cc)
                    bf[(nt+1)&1][cc] = ld8(WTv + ((nt+1)*16 + col)*96 + cc*32 + quad*8);
            }
            int o = nt*16 + col;
            int h = (o >= 96) ? 1 : 0;
            int d = o - h*96;
            float bo = bv[o];
            #pragma unroll
            for (int ti = 0; ti < 2; ++ti) {
                floatx4 acc = {0.f, 0.f, 0.f, 0.f};
                #pragma unroll
                for (int cc = 0; cc < 3; ++cc)
                    acc = MFMA16(at[ti][cc], bf[nt&1][cc], acc);
                shortx4 val;
                val.x = (t0T[ti]+0 < NK) ? f2s(acc[0] + bo) : (short)0;
                val.y = (t0T[ti]+1 < NK) ? f2s(acc[1] + bo) : (short)0;
                val.z = (t0T[ti]+2 < NK) ? f2s(acc[2] + bo) : (short)0;
                val.w = (t0T[ti]+3 < NK) ? f2s(acc[3] + bo) : (short)0;
                *reinterpret_cast<shortx4*>(vt + ((long)(bT[ti]*2 + h)*VROWS + d)*NKPV + t0T[ti]) = val;
            }
        }
    }
}

// ---------------------------------------------------------------------------
// Kernel 3: MFMA attention (round-4 structure, best measured). ONE wave per
// block, TWO 16-q-row tiles per wave, streamed K/V from L2.
// NEW vs r4: K ring deepened to dist-2 (3 buffers); V(0) prefetch issued one
// S-iteration earlier (kt==11) for more latency cover.
// ---------------------------------------------------------------------------
__global__ __launch_bounds__(64, 2) void attn_kernel(
    const short* __restrict__ qb, const short* __restrict__ kb,
    const short* __restrict__ vt, const short* __restrict__ relc,
    float* __restrict__ out)
{
    __shared__ __align__(16) short smem[2][16][232];   // 14848 B

    int lane = threadIdx.x & 63;
    int quad = lane >> 4, col = lane & 15;

    int bid = blockIdx.x;                      // 3200 = 8 * 400
    int wt  = (bid & 7) * 400 + (bid >> 3);    // XCD-contiguous ranges (25 waves/bh)
    int bh  = wt / 25;
    int tp  = wt % 25;
    int q0  = tp * 32;                         // rows q0..q0+31

    // Q A-fragments for both tiles
    const short* qrow = qb + ((long)bh*NQP + q0)*96;
    short8 aq[2][3];
    #pragma unroll
    for (int ti = 0; ti < 2; ++ti)
        #pragma unroll
        for (int c = 0; c < 3; ++c)
            aq[ti][c] = ld8(qrow + (ti*16 + col)*96 + c*32 + quad*8);

    // E = Q Rel^T with rel-fragment register double-buffer
    short8 rf[2][3];
    #pragma unroll
    for (int c = 0; c < 3; ++c)
        rf[0][c] = ld8(relc + col*96 + c*32 + quad*8);
    #pragma unroll
    for (int rt = 0; rt < 7; ++rt) {
        if (rt < 6) {
            #pragma unroll
            for (int c = 0; c < 3; ++c)
                rf[(rt+1)&1][c] = ld8(relc + ((rt+1)*16 + col)*96 + c*32 + quad*8);
        }
        #pragma unroll
        for (int ti = 0; ti < 2; ++ti) {
            floatx4 acc = {0.f, 0.f, 0.f, 0.f};
            #pragma unroll
            for (int c = 0; c < 3; ++c)
                acc = MFMA16(aq[ti][c], rf[rt&1][c], acc);
            #pragma unroll
            for (int reg = 0; reg < 4; ++reg)
                smem[ti][quad*4 + reg][rt*16 + col] = f2s(acc[reg]);
        }
    }

    // issue K(0) and K(1) loads now — latency hides under the bias gather
    const short* kbase = kb + (long)bh*NKP*96;
    short8 kf[3][3];
    #pragma unroll
    for (int c = 0; c < 3; ++c)
        kf[0][c] = ld8(kbase + col*96 + c*32 + quad*8);
    #pragma unroll
    for (int c = 0; c < 3; ++c)
        kf[1][c] = ld8(kbase + (16 + col)*96 + c*32 + quad*8);

    // per-row q spatial coords (8 rows per lane: 2 tiles x 4 regs)
    int qyo[2][4], qxo[2][4];
    #pragma unroll
    for (int ti = 0; ti < 2; ++ti)
        #pragma unroll
        for (int reg = 0; reg < 4; ++reg) {
            int qq = q0 + ti*16 + quad*4 + reg;
            int jj = (qq > 0) ? (qq - 1) : 0;
            qyo[ti][reg] = jj / QW;
            qxo[ti][reg] = jj % QW;
        }

    // hoisted rel-bias gather: 13 kt x 8 rows -> 52 packed-f16 regs
    unsigned bpk[2][13][2];
    #pragma unroll
    for (int kt = 0; kt < 13; ++kt) {
        int k  = kt*16 + col;
        int kk = (k > 0) ? (k - 1) : 0;
        int ky = kk / 14;  ky = (ky < 13) ? ky : 13;
        int kx = kk - 14*ky;
        int oh  = 26 - 2*ky;
        int ow2 = 26 - 2*kx;
        #pragma unroll
        for (int ti = 0; ti < 2; ++ti) {
            float bs[4];
            #pragma unroll
            for (int reg = 0; reg < 4; ++reg) {
                const short* er = &smem[ti][quad*4 + reg][0];
                float bias = s2f(er[qyo[ti][reg] + oh]) + s2f(er[54 + qxo[ti][reg] + ow2]);
                if (kt == 0) bias = (col == 0) ? 0.f : bias;                        // CLS col
                if (q0 == 0 && ti == 0 && reg == 0) bias = (quad == 0) ? 0.f : bias; // CLS row
                bs[reg] = bias;
            }
            bpk[ti][kt][0] = pkhf(bs[0], bs[1]);
            bpk[ti][kt][1] = pkhf(bs[2], bs[3]);
        }
    }

    // fused S2 = log2e*(Q K^T + rel bias); P = exp2(S2) -> overwrites E.
    // K dist-2 register ring; V(0) prefetch issued at kt==11.
    const short* vbase = vt + (long)bh*VROWS*NKPV;
    short8 vf[2][7];
    #pragma unroll
    for (int kt = 0; kt < 13; ++kt) {
        if (kt < 11) {
            #pragma unroll
            for (int c = 0; c < 3; ++c)
                kf[(kt+2)%3][c] = ld8(kbase + ((kt+2)*16 + col)*96 + c*32 + quad*8);
        } else if (kt == 11) {
            #pragma unroll
            for (int nt = 0; nt < 7; ++nt)
                vf[0][nt] = ld8(vbase + (nt*16 + col)*NKPV + quad*8);
        }
        int k = kt*16 + col;
        __builtin_amdgcn_s_setprio(1);
        floatx4 accA = {0.f, 0.f, 0.f, 0.f};
        floatx4 accB = {0.f, 0.f, 0.f, 0.f};
        #pragma unroll
        for (int c = 0; c < 3; ++c) {
            accA = MFMA16(aq[0][c], kf[kt%3][c], accA);
            accB = MFMA16(aq[1][c], kf[kt%3][c], accB);
        }
        __builtin_amdgcn_s_setprio(0);
        unsigned a0 = bpk[0][kt][0], a1 = bpk[0][kt][1];
        unsigned b0 = bpk[1][kt][0], b1 = bpk[1][kt][1];
        smem[0][quad*4 + 0][k] = f2s(__builtin_amdgcn_exp2f(accA[0] + hflo(a0)));
        smem[0][quad*4 + 1][k] = f2s(__builtin_amdgcn_exp2f(accA[1] + hfhi(a0)));
        smem[0][quad*4 + 2][k] = f2s(__builtin_amdgcn_exp2f(accA[2] + hflo(a1)));
        smem[0][quad*4 + 3][k] = f2s(__builtin_amdgcn_exp2f(accA[3] + hfhi(a1)));
        smem[1][quad*4 + 0][k] = f2s(__builtin_amdgcn_exp2f(accB[0] + hflo(b0)));
        smem[1][quad*4 + 1][k] = f2s(__builtin_amdgcn_exp2f(accB[1] + hfhi(b0)));
        smem[1][quad*4 + 2][k] = f2s(__builtin_amdgcn_exp2f(accB[2] + hflo(b1)));
        smem[1][quad*4 + 3][k] = f2s(__builtin_amdgcn_exp2f(accB[3] + hfhi(b1)));
    }
    #pragma unroll
    for (int ti = 0; ti < 2; ++ti)             // zero PV pad cols 208..223
        #pragma unroll
        for (int reg = 0; reg < 4; ++reg)
            smem[ti][quad*4 + reg][208 + col] = 0;

    // O = P V (7 K-chunks of 32; 6 V n-tiles + ones-row n-tile = row sums)
    // V fragments double-buffered: V(c+1) issued before PV-MFMA(c).
    floatx4 o[2][7];
    #pragma unroll
    for (int ti = 0; ti < 2; ++ti)
        #pragma unroll
        for (int nt = 0; nt < 7; ++nt) o[ti][nt] = floatx4{0.f, 0.f, 0.f, 0.f};
    #pragma unroll
    for (int c = 0; c < 7; ++c) {
        if (c < 6) {
            #pragma unroll
            for (int nt = 0; nt < 7; ++nt)
                vf[(c+1)&1][nt] = ld8(vbase + (nt*16 + col)*NKPV + (c+1)*32 + quad*8);
        }
        short8 apA = ld8(&smem[0][col][c*32 + quad*8]);
        short8 apB = ld8(&smem[1][col][c*32 + quad*8]);
        __builtin_amdgcn_s_setprio(1);
        #pragma unroll
        for (int nt = 0; nt < 7; ++nt) {
            o[0][nt] = MFMA16(apA, vf[c&1][nt], o[0][nt]);
            o[1][nt] = MFMA16(apB, vf[c&1][nt], o[1][nt]);
        }
        __builtin_amdgcn_s_setprio(0);
    }

    // epilogue: broadcast row sums, normalize, +residual
    float inv[2][4];
    #pragma unroll
    for (int ti = 0; ti < 2; ++ti)
        #pragma unroll
        for (int reg = 0; reg < 4; ++reg) {
            float srow = __shfl(o[ti][6][reg], lane & 48, 64);
            inv[ti][reg] = 1.0f / srow;
        }
    int b = bh >> 1, h = bh & 1;
    #pragma unroll
    for (int ti = 0; ti < 2; ++ti)
        #pragma unroll
        for (int nt = 0; nt < 6; ++nt) {
            int ch = nt*16 + col;
            #pragma unroll
            for (int reg = 0; reg < 4; ++reg) {
                int q = q0 + ti*16 + quad*4 + reg;
                if (q < NQ) {
                    float val = o[ti][nt][reg] * inv[ti][reg];
                    if (q > 0) val += s2f(qb[((long)bh*NQP + q)*96 + ch]);
                    out[((long)b*NQ + q)*192 + h*96 + ch] = val;
                }
            }
        }
}

// ---------------------------------------------------------------------------
extern "C" void kernel_launch(void* const* d_in, const int* in_sizes, int n_in,
                              void* d_out, int out_size, void* d_ws, size_t ws_size,
                              hipStream_t stream)
{
    const float* hs    = (const float*)d_in[0];
    const float* Wq    = (const float*)d_in[1];
    const float* bq    = (const float*)d_in[2];
    const float* Wk    = (const float*)d_in[3];
    const float* bk    = (const float*)d_in[4];
    const float* Wv    = (const float*)d_in[5];
    const float* bv    = (const float*)d_in[6];
    const float* pqw   = (const float*)d_in[7];
    const float* pkw   = (const float*)d_in[8];
    const float* pvw   = (const float*)d_in[9];
    const float* gq    = (const float*)d_in[10];
    const float* betaq = (const float*)d_in[11];
    const float* gk    = (const float*)d_in[12];
    const float* betak = (const float*)d_in[13];
    const float* gv    = (const float*)d_in[14];
    const float* betav = (const float*)d_in[15];
    const float* relh  = (const float*)d_in[16];
    const float* relw  = (const float*)d_in[17];
    float* out = (float*)d_out;

    // workspace carve (bf16 as short) — ~46.3 MB
    short* pq   = (short*)d_ws;                  // [64][800][96]
    short* pk   = pq  + (long)B_*NQP*CIN;        // [64][208][96]
    short* pv   = pk  + (long)B_*NKP*CIN;        // [64][208][96]
    short* qb   = pv  + (long)B_*NKP*CIN;        // [128][800][96]
    short* kb   = qb  + (long)128*NQP*96;        // [128][208][96]
    short* vt   = kb  + (long)128*NKP*96;        // [128][112][224]
    short* WTq  = vt  + (long)128*VROWS*NKPV;    // [192][96]
    short* WTk  = WTq + 192*96;
    short* WTv  = WTk + 192*96;
    short* relc = WTv + 192*96;                  // [112][96]
    float* cwqT = (float*)(relc + 112*96);       // [9][96] fp32
    float* cwkT = cwqT + 9*96;
    float* cwvT = cwkT + 9*96;

    prep_kernel<<<2829, 256, 0, stream>>>(Wq, Wk, Wv, relh, relw,
                                          pqw, pkw, pvw,
                                          WTq, WTk, WTv, relc, vt,
                                          cwqT, cwkT, cwvT);

    pool_ln_kernel<<<(B_*1008)/16, 256, 0, stream>>>(
        hs, cwqT, cwkT, cwvT, gq, betaq, gk, betak, gv, betav, pq, pk, pv);

    proj_mfma_kernel<<<2432/4, 256, 0, stream>>>(
        pq, pk, pv, WTq, WTk, WTv, bq, bk, bv, qb, kb, vt);

    attn_kernel<<<3200, 64, 0, stream>>>(qb, kb, vt, relc, out);
}

// Round 8
// 240.446 us; speedup vs baseline: 1.0368x; 1.0004x over previous
//
#include <hip/hip_runtime.h>
#include <hip/hip_bf16.h>
#include <hip/hip_fp16.h>

#define B_    64
#define HFS   56
#define CIN   96
#define NQ    785
#define NK    197
#define QW    28
#define KW    14
#define NTOT  3137    // 56*56+1
#define NQP   800     // q tokens padded to 16
#define NKP   208     // kv tokens padded to 16
#define NKPV  224     // PV K-dim padded to 32
#define VROWS 112     // 96 v channels + ones row + 15 zero rows
#define KSCL  0.10206207261596575f   // 96^-0.5, folded into Wk
#define LOG2E 1.4426950408889634f    // exp(x) = exp2(x*log2e), folded into Wk/relc
#define KSCL2 (KSCL*LOG2E)

typedef __attribute__((ext_vector_type(8))) short short8;
typedef __attribute__((ext_vector_type(4))) short shortx4;
typedef __attribute__((ext_vector_type(4))) float floatx4;

__device__ __forceinline__ short f2s(float x) {
    __hip_bfloat16 h = __float2bfloat16(x);
    return *reinterpret_cast<short*>(&h);
}
__device__ __forceinline__ float s2f(short s) {
    __hip_bfloat16 h; *reinterpret_cast<short*>(&h) = s;
    return __bfloat162float(h);
}
__device__ __forceinline__ short8 ld8(const short* p) {
    return *reinterpret_cast<const short8*>(p);
}
__device__ __forceinline__ unsigned pkbf(float a, float b) {
    return (unsigned)(unsigned short)f2s(a) | ((unsigned)(unsigned short)f2s(b) << 16);
}
__device__ __forceinline__ unsigned pkhf(float a, float b) {
    __half2 h = __floats2half2_rn(a, b);
    return *reinterpret_cast<unsigned*>(&h);
}
__device__ __forceinline__ float hflo(unsigned w) {
    __half2 h = *reinterpret_cast<__half2*>(&w);
    return __half2float(__low2half(h));
}
__device__ __forceinline__ float hfhi(unsigned w) {
    __half2 h = *reinterpret_cast<__half2*>(&w);
    return __half2float(__high2half(h));
}

#define MFMA16(a,b,c) __builtin_amdgcn_mfma_f32_16x16x32_bf16((a),(b),(c),0,0,0)

// ---------------------------------------------------------------------------
// Kernel 0: prep = repack W^T (bf16; Wk pre-scaled by 96^-0.5*log2e), rel
// matrix (pre-scaled by log2e), vt pad init, conv-weight transposes.
// (r6 scalar version — reverted for bisection hygiene)
// ---------------------------------------------------------------------------
__global__ void prep_kernel(const float* __restrict__ Wq, const float* __restrict__ Wk,
                            const float* __restrict__ Wv, const float* __restrict__ relh,
                            const float* __restrict__ relw,
                            const float* __restrict__ pqw, const float* __restrict__ pkw,
                            const float* __restrict__ pvw,
                            short* __restrict__ WTq, short* __restrict__ WTk,
                            short* __restrict__ WTv, short* __restrict__ relc,
                            short* __restrict__ vt,
                            float* __restrict__ cwqT, float* __restrict__ cwkT,
                            float* __restrict__ cwvT)
{
    int i = blockIdx.x * 256 + threadIdx.x;           // 724000 total
    if (i < 18432)      { int o = i/96, c = i%96;              WTq[o*96+c] = f2s(Wq[c*192+o]); }
    else if (i < 36864) { int j = i-18432; int o=j/96,c=j%96;  WTk[o*96+c] = f2s(Wk[c*192+o]*KSCL2); }
    else if (i < 55296) { int j = i-36864; int o=j/96,c=j%96;  WTv[o*96+c] = f2s(Wv[c*192+o]); }
    else if (i < 66048) {
        int j = i - 55296;  int r = j/96, c = j%96;            // 112*96
        float v = (r < 54) ? relh[r*96+c] : ((r < 108) ? relw[(r-54)*96+c] : 0.f);
        relc[r*96+c] = f2s(v*LOG2E);
    } else if (i < 721408) {
        int j2 = i - 66048;                                     // 128 * 5120
        int bh = j2 / 5120, r = j2 % 5120;
        int row, tok; short val;
        if (r < 3584) { row = 96 + r/224; tok = r%224;
                        val = (row == 96 && tok < NK) ? (short)0x3F80 : (short)0; }
        else          { int rr = r-3584; row = rr/16; tok = 208 + (rr%16); val = 0; }
        vt[((long)bh*VROWS + row)*NKPV + tok] = val;
    } else if (i < 724000) {
        int j = i - 721408;                                     // 3 * 864
        int w = j / 864, r = j % 864;
        int c = r / 9, off = r % 9;
        const float* src = (w == 0) ? pqw : (w == 1) ? pkw : pvw;
        float*       dst = (w == 0) ? cwqT : (w == 1) ? cwkT : cwvT;
        dst[off*96 + c] = src[c*9 + off];
    }
}

// ---------------------------------------------------------------------------
// Kernel 1: depthwise 3x3 pool conv + LayerNorm -> bf16 pooled tokens.
// 4 tokens per wave: 16 lanes per token, 6 channels per lane.
// All 9 taps' h-values prefetched into registers in one burst.
// (r6 version, unchanged)
// ---------------------------------------------------------------------------
__device__ __forceinline__ void red16_2(float& s, float& ss) {
    #pragma unroll
    for (int off = 8; off >= 1; off >>= 1) {
        s  += __shfl_xor(s,  off, 16);
        ss += __shfl_xor(ss, off, 16);
    }
}

__device__ __forceinline__ void ln6_store(const float* x, float m, float r,
    const float* __restrict__ g, const float* __restrict__ beta,
    int c0, short* __restrict__ outp)
{
    float2 g0 = *reinterpret_cast<const float2*>(g + c0);
    float2 g1 = *reinterpret_cast<const float2*>(g + c0 + 2);
    float2 g2 = *reinterpret_cast<const float2*>(g + c0 + 4);
    float2 b0 = *reinterpret_cast<const float2*>(beta + c0);
    float2 b1 = *reinterpret_cast<const float2*>(beta + c0 + 2);
    float2 b2 = *reinterpret_cast<const float2*>(beta + c0 + 4);
    unsigned o0 = pkbf((x[0]-m)*r*g0.x + b0.x, (x[1]-m)*r*g0.y + b0.y);
    unsigned o1 = pkbf((x[2]-m)*r*g1.x + b1.x, (x[3]-m)*r*g1.y + b1.y);
    unsigned o2 = pkbf((x[4]-m)*r*g2.x + b2.x, (x[5]-m)*r*g2.y + b2.y);
    *reinterpret_cast<unsigned*>(outp)     = o0;
    *reinterpret_cast<unsigned*>(outp + 2) = o1;
    *reinterpret_cast<unsigned*>(outp + 4) = o2;
}

__device__ __forceinline__ void zero6(short* __restrict__ outp) {
    *reinterpret_cast<unsigned*>(outp)     = 0u;
    *reinterpret_cast<unsigned*>(outp + 2) = 0u;
    *reinterpret_cast<unsigned*>(outp + 4) = 0u;
}

__global__ __launch_bounds__(256) void pool_ln_kernel(
    const float* __restrict__ hs,
    const float* __restrict__ cwqT, const float* __restrict__ cwkT, const float* __restrict__ cwvT,
    const float* __restrict__ gq, const float* __restrict__ betaq,
    const float* __restrict__ gk, const float* __restrict__ betak,
    const float* __restrict__ gv, const float* __restrict__ betav,
    short* __restrict__ pq, short* __restrict__ pk, short* __restrict__ pv)
{
    const int wid  = threadIdx.x >> 6;
    const int lane = threadIdx.x & 63;
    const int sub  = lane >> 4;               // token within wave
    const int li   = lane & 15;               // lane within token group
    const int c0   = li * 6;                  // channels c0..c0+5
    const int gid  = blockIdx.x * 4 + wid;    // 16128 waves total
    const int b    = gid / 252;
    const int slot = gid % 252;               // 200 q-slots + 52 kv-slots
    const long hb  = (long)b * NTOT * CIN;

    if (slot < 200) {                          // ---- q path (stride 2) ----
        int t = slot*4 + sub;
        short* outp = pq + ((long)b*NQP + t)*CIN + c0;
        if (t >= NQ) { zero6(outp); return; }
        float x[6];
        #pragma unroll
        for (int i = 0; i < 6; ++i) x[i] = 0.f;
        if (t == 0) {
            const float* hp = hs + hb + c0;
            float2 a0 = *reinterpret_cast<const float2*>(hp);
            float2 a1 = *reinterpret_cast<const float2*>(hp + 2);
            float2 a2 = *reinterpret_cast<const float2*>(hp + 4);
            x[0]=a0.x; x[1]=a0.y; x[2]=a1.x; x[3]=a1.y; x[4]=a2.x; x[5]=a2.y;
        } else {
            int j = t - 1, oy = j / QW, ox = j % QW;
            float2 hbuf[9][3];
            #pragma unroll
            for (int tap = 0; tap < 9; ++tap) {
                int dy = tap / 3, dx = tap % 3;
                int iy = oy*2 - 1 + dy;
                int ix = ox*2 - 1 + dx;
                if (iy >= 0 && iy < HFS && ix >= 0 && ix < HFS) {
                    const float* hp = hs + hb + (long)(1 + iy*HFS + ix)*CIN + c0;
                    hbuf[tap][0] = *reinterpret_cast<const float2*>(hp);
                    hbuf[tap][1] = *reinterpret_cast<const float2*>(hp + 2);
                    hbuf[tap][2] = *reinterpret_cast<const float2*>(hp + 4);
                } else {
                    hbuf[tap][0] = float2{0.f, 0.f};
                    hbuf[tap][1] = float2{0.f, 0.f};
                    hbuf[tap][2] = float2{0.f, 0.f};
                }
            }
            #pragma unroll
            for (int tap = 0; tap < 9; ++tap) {
                const float* wp = cwqT + tap*96 + c0;
                float2 w0 = *reinterpret_cast<const float2*>(wp);
                float2 w1 = *reinterpret_cast<const float2*>(wp + 2);
                float2 w2 = *reinterpret_cast<const float2*>(wp + 4);
                x[0] = fmaf(hbuf[tap][0].x, w0.x, x[0]); x[1] = fmaf(hbuf[tap][0].y, w0.y, x[1]);
                x[2] = fmaf(hbuf[tap][1].x, w1.x, x[2]); x[3] = fmaf(hbuf[tap][1].y, w1.y, x[3]);
                x[4] = fmaf(hbuf[tap][2].x, w2.x, x[4]); x[5] = fmaf(hbuf[tap][2].y, w2.y, x[5]);
            }
        }
        float s  = (x[0]+x[1]) + (x[2]+x[3]) + (x[4]+x[5]);
        float ss = fmaf(x[0],x[0], fmaf(x[1],x[1], fmaf(x[2],x[2],
                   fmaf(x[3],x[3], fmaf(x[4],x[4], x[5]*x[5])))));
        red16_2(s, ss);
        float m   = s * (1.f/96.f);
        float var = ss * (1.f/96.f) - m*m;
        float r   = rsqrtf(var + 1e-5f);
        ln6_store(x, m, r, gq, betaq, c0, outp);
    } else {                                   // ---- k+v fused (stride 4) ----
        int tok = (slot - 200)*4 + sub;
        short* ok_ = pk + ((long)b*NKP + tok)*CIN + c0;
        short* ov_ = pv + ((long)b*NKP + tok)*CIN + c0;
        if (tok >= NK) { zero6(ok_); zero6(ov_); return; }
        float xk[6], xv[6];
        #pragma unroll
        for (int i = 0; i < 6; ++i) { xk[i] = 0.f; xv[i] = 0.f; }
        if (tok == 0) {
            const float* hp = hs + hb + c0;
            float2 a0 = *reinterpret_cast<const float2*>(hp);
            float2 a1 = *reinterpret_cast<const float2*>(hp + 2);
            float2 a2 = *reinterpret_cast<const float2*>(hp + 4);
            xk[0]=xv[0]=a0.x; xk[1]=xv[1]=a0.y; xk[2]=xv[2]=a1.x;
            xk[3]=xv[3]=a1.y; xk[4]=xv[4]=a2.x; xk[5]=xv[5]=a2.y;
        } else {
            int j = tok - 1, oy = j / KW, ox = j % KW;
            float2 hbuf[9][3];
            #pragma unroll
            for (int tap = 0; tap < 9; ++tap) {
                int dy = tap / 3, dx = tap % 3;
                int iy = oy*4 - 1 + dy;
                int ix = ox*4 - 1 + dx;
                if (iy >= 0 && iy < HFS && ix >= 0 && ix < HFS) {
                    const float* hp = hs + hb + (long)(1 + iy*HFS + ix)*CIN + c0;
                    hbuf[tap][0] = *reinterpret_cast<const float2*>(hp);
                    hbuf[tap][1] = *reinterpret_cast<const float2*>(hp + 2);
                    hbuf[tap][2] = *reinterpret_cast<const float2*>(hp + 4);
                } else {
                    hbuf[tap][0] = float2{0.f, 0.f};
                    hbuf[tap][1] = float2{0.f, 0.f};
                    hbuf[tap][2] = float2{0.f, 0.f};
                }
            }
            #pragma unroll
            for (int tap = 0; tap < 9; ++tap) {
                int wo = tap*96 + c0;
                float2 k0 = *reinterpret_cast<const float2*>(cwkT + wo);
                float2 k1 = *reinterpret_cast<const float2*>(cwkT + wo + 2);
                float2 k2 = *reinterpret_cast<const float2*>(cwkT + wo + 4);
                float2 v0 = *reinterpret_cast<const float2*>(cwvT + wo);
                float2 v1 = *reinterpret_cast<const float2*>(cwvT + wo + 2);
                float2 v2 = *reinterpret_cast<const float2*>(cwvT + wo + 4);
                xk[0] = fmaf(hbuf[tap][0].x, k0.x, xk[0]); xk[1] = fmaf(hbuf[tap][0].y, k0.y, xk[1]);
                xk[2] = fmaf(hbuf[tap][1].x, k1.x, xk[2]); xk[3] = fmaf(hbuf[tap][1].y, k1.y, xk[3]);
                xk[4] = fmaf(hbuf[tap][2].x, k2.x, xk[4]); xk[5] = fmaf(hbuf[tap][2].y, k2.y, xk[5]);
                xv[0] = fmaf(hbuf[tap][0].x, v0.x, xv[0]); xv[1] = fmaf(hbuf[tap][0].y, v0.y, xv[1]);
                xv[2] = fmaf(hbuf[tap][1].x, v1.x, xv[2]); xv[3] = fmaf(hbuf[tap][1].y, v1.y, xv[3]);
                xv[4] = fmaf(hbuf[tap][2].x, v2.x, xv[4]); xv[5] = fmaf(hbuf[tap][2].y, v2.y, xv[5]);
            }
        }
        float sk  = (xk[0]+xk[1]) + (xk[2]+xk[3]) + (xk[4]+xk[5]);
        float ssk = fmaf(xk[0],xk[0], fmaf(xk[1],xk[1], fmaf(xk[2],xk[2],
                    fmaf(xk[3],xk[3], fmaf(xk[4],xk[4], xk[5]*xk[5])))));
        float sv  = (xv[0]+xv[1]) + (xv[2]+xv[3]) + (xv[4]+xv[5]);
        float ssv = fmaf(xv[0],xv[0], fmaf(xv[1],xv[1], fmaf(xv[2],xv[2],
                    fmaf(xv[3],xv[3], fmaf(xv[4],xv[4], xv[5]*xv[5])))));
        red16_2(sk, ssk);
        red16_2(sv, ssv);
        float mk = sk * (1.f/96.f), vark = ssk * (1.f/96.f) - mk*mk;
        float mv = sv * (1.f/96.f), varv = ssv * (1.f/96.f) - mv*mv;
        float rk = rsqrtf(vark + 1e-5f);
        float rv = rsqrtf(varv + 1e-5f);
        ln6_store(xk, mk, rk, gk, betak, c0, ok_);
        ln6_store(xv, mv, rv, gv, betav, c0, ov_);
    }
}

// ---------------------------------------------------------------------------
// Kernel 2: projections as MFMA GEMM. FOUR 16-token tiles per wave sharing
// every weight-fragment load (was 2): per-load MFMA chains 2->4, weight
// loads per unit work halved again. 1216 wave-units total.
// q/k: swapped orientation; v: original orientation (transposed store).
// ---------------------------------------------------------------------------
__global__ __launch_bounds__(256) void proj_mfma_kernel(
    const short* __restrict__ pq, const short* __restrict__ pk, const short* __restrict__ pv,
    const short* __restrict__ WTq, const short* __restrict__ WTk, const short* __restrict__ WTv,
    const float* __restrict__ bq, const float* __restrict__ bk, const float* __restrict__ bv,
    short* __restrict__ qb, short* __restrict__ kb, short* __restrict__ vt)
{
    int wid  = threadIdx.x >> 6;
    int lane = threadIdx.x & 63;
    int quad = lane >> 4, col = lane & 15;
    int wt = blockIdx.x * 4 + wid;              // 1216 wave-units total

    if (wt < 1008) {                            // ---- q and k: swapped ----
        const short *A, *WT; const float* bias; short* outp;
        int ntokp, row0; float bsc;
        if (wt < 800) { A = pq; WT = WTq; bias = bq; outp = qb; ntokp = NQP; row0 = wt*64; bsc = 1.f; }
        else          { A = pk; WT = WTk; bias = bk; outp = kb; ntokp = NKP; row0 = (wt-800)*64; bsc = KSCL2; }

        short8 bt[4][3];
        #pragma unroll
        for (int ti = 0; ti < 4; ++ti)
            #pragma unroll
            for (int cc = 0; cc < 3; ++cc)
                bt[ti][cc] = ld8(A + (long)(row0 + ti*16 + col)*96 + cc*32 + quad*8);

        int bT[4], tokT[4];
        #pragma unroll
        for (int ti = 0; ti < 4; ++ti) {
            int r = row0 + ti*16;
            bT[ti] = r / ntokp;
            tokT[ti] = (r % ntokp) + col;
        }

        short8 af[2][3];
        #pragma unroll
        for (int cc = 0; cc < 3; ++cc)
            af[0][cc] = ld8(WT + col*96 + cc*32 + quad*8);

        #pragma unroll
        for (int nt = 0; nt < 12; ++nt) {
            if (nt < 11) {
                #pragma unroll
                for (int cc = 0; cc < 3; ++cc)
                    af[(nt+1)&1][cc] = ld8(WT + ((nt+1)*16 + col)*96 + cc*32 + quad*8);
            }
            int o0 = nt*16 + quad*4;            // 4 consecutive outputs
            float4 bo = *reinterpret_cast<const float4*>(bias + o0);
            int h  = (o0 >= 96) ? 1 : 0;
            int d0 = o0 - h*96;
            #pragma unroll
            for (int ti = 0; ti < 4; ++ti) {
                floatx4 acc = {0.f, 0.f, 0.f, 0.f};
                #pragma unroll
                for (int cc = 0; cc < 3; ++cc)
                    acc = MFMA16(af[nt&1][cc], bt[ti][cc], acc);
                shortx4 val;
                val.x = f2s(acc[0] + bo.x*bsc);
                val.y = f2s(acc[1] + bo.y*bsc);
                val.z = f2s(acc[2] + bo.z*bsc);
                val.w = f2s(acc[3] + bo.w*bsc);
                *reinterpret_cast<shortx4*>(outp + ((long)(bT[ti]*2 + h)*ntokp + tokT[ti])*96 + d0) = val;
            }
        }
    } else {                                    // ---- v: original orient ----
        int row0 = (wt - 1008) * 64;
        short8 at[4][3];
        #pragma unroll
        for (int ti = 0; ti < 4; ++ti)
            #pragma unroll
            for (int cc = 0; cc < 3; ++cc)
                at[ti][cc] = ld8(pv + (long)(row0 + ti*16 + col)*96 + cc*32 + quad*8);

        int bT[4], t0T[4];
        #pragma unroll
        for (int ti = 0; ti < 4; ++ti) {
            int r = row0 + ti*16;
            bT[ti] = r / NKP;
            t0T[ti] = (r % NKP) + quad*4;       // 4 consecutive tokens
        }

        short8 bf[2][3];
        #pragma unroll
        for (int cc = 0; cc < 3; ++cc)
            bf[0][cc] = ld8(WTv + col*96 + cc*32 + quad*8);

        #pragma unroll
        for (int nt = 0; nt < 12; ++nt) {
            if (nt < 11) {
                #pragma unroll
                for (int cc = 0; cc < 3; ++cc)
                    bf[(nt+1)&1][cc] = ld8(WTv + ((nt+1)*16 + col)*96 + cc*32 + quad*8);
            }
            int o = nt*16 + col;
            int h = (o >= 96) ? 1 : 0;
            int d = o - h*96;
            float bo = bv[o];
            #pragma unroll
            for (int ti = 0; ti < 4; ++ti) {
                floatx4 acc = {0.f, 0.f, 0.f, 0.f};
                #pragma unroll
                for (int cc = 0; cc < 3; ++cc)
                    acc = MFMA16(at[ti][cc], bf[nt&1][cc], acc);
                shortx4 val;
                val.x = (t0T[ti]+0 < NK) ? f2s(acc[0] + bo) : (short)0;
                val.y = (t0T[ti]+1 < NK) ? f2s(acc[1] + bo) : (short)0;
                val.z = (t0T[ti]+2 < NK) ? f2s(acc[2] + bo) : (short)0;
                val.w = (t0T[ti]+3 < NK) ? f2s(acc[3] + bo) : (short)0;
                *reinterpret_cast<shortx4*>(vt + ((long)(bT[ti]*2 + h)*VROWS + d)*NKPV + t0T[ti]) = val;
            }
        }
    }
}

// ---------------------------------------------------------------------------
// Kernel 3: MFMA attention (round-6 structure, best measured). ONE wave per
// block, TWO 16-q-row tiles per wave, streamed K/V from L2, K dist-2 ring.
// ---------------------------------------------------------------------------
__global__ __launch_bounds__(64, 2) void attn_kernel(
    const short* __restrict__ qb, const short* __restrict__ kb,
    const short* __restrict__ vt, const short* __restrict__ relc,
    float* __restrict__ out)
{
    __shared__ __align__(16) short smem[2][16][232];   // 14848 B

    int lane = threadIdx.x & 63;
    int quad = lane >> 4, col = lane & 15;

    int bid = blockIdx.x;                      // 3200 = 8 * 400
    int wt  = (bid & 7) * 400 + (bid >> 3);    // XCD-contiguous ranges (25 waves/bh)
    int bh  = wt / 25;
    int tp  = wt % 25;
    int q0  = tp * 32;                         // rows q0..q0+31

    // Q A-fragments for both tiles
    const short* qrow = qb + ((long)bh*NQP + q0)*96;
    short8 aq[2][3];
    #pragma unroll
    for (int ti = 0; ti < 2; ++ti)
        #pragma unroll
        for (int c = 0; c < 3; ++c)
            aq[ti][c] = ld8(qrow + (ti*16 + col)*96 + c*32 + quad*8);

    // E = Q Rel^T with rel-fragment register double-buffer
    short8 rf[2][3];
    #pragma unroll
    for (int c = 0; c < 3; ++c)
        rf[0][c] = ld8(relc + col*96 + c*32 + quad*8);
    #pragma unroll
    for (int rt = 0; rt < 7; ++rt) {
        if (rt < 6) {
            #pragma unroll
            for (int c = 0; c < 3; ++c)
                rf[(rt+1)&1][c] = ld8(relc + ((rt+1)*16 + col)*96 + c*32 + quad*8);
        }
        #pragma unroll
        for (int ti = 0; ti < 2; ++ti) {
            floatx4 acc = {0.f, 0.f, 0.f, 0.f};
            #pragma unroll
            for (int c = 0; c < 3; ++c)
                acc = MFMA16(aq[ti][c], rf[rt&1][c], acc);
            #pragma unroll
            for (int reg = 0; reg < 4; ++reg)
                smem[ti][quad*4 + reg][rt*16 + col] = f2s(acc[reg]);
        }
    }

    // issue K(0) and K(1) loads now — latency hides under the bias gather
    const short* kbase = kb + (long)bh*NKP*96;
    short8 kf[3][3];
    #pragma unroll
    for (int c = 0; c < 3; ++c)
        kf[0][c] = ld8(kbase + col*96 + c*32 + quad*8);
    #pragma unroll
    for (int c = 0; c < 3; ++c)
        kf[1][c] = ld8(kbase + (16 + col)*96 + c*32 + quad*8);

    // per-row q spatial coords (8 rows per lane: 2 tiles x 4 regs)
    int qyo[2][4], qxo[2][4];
    #pragma unroll
    for (int ti = 0; ti < 2; ++ti)
        #pragma unroll
        for (int reg = 0; reg < 4; ++reg) {
            int qq = q0 + ti*16 + quad*4 + reg;
            int jj = (qq > 0) ? (qq - 1) : 0;
            qyo[ti][reg] = jj / QW;
            qxo[ti][reg] = jj % QW;
        }

    // hoisted rel-bias gather: 13 kt x 8 rows -> 52 packed-f16 regs
    unsigned bpk[2][13][2];
    #pragma unroll
    for (int kt = 0; kt < 13; ++kt) {
        int k  = kt*16 + col;
        int kk = (k > 0) ? (k - 1) : 0;
        int ky = kk / 14;  ky = (ky < 13) ? ky : 13;
        int kx = kk - 14*ky;
        int oh  = 26 - 2*ky;
        int ow2 = 26 - 2*kx;
        #pragma unroll
        for (int ti = 0; ti < 2; ++ti) {
            float bs[4];
            #pragma unroll
            for (int reg = 0; reg < 4; ++reg) {
                const short* er = &smem[ti][quad*4 + reg][0];
                float bias = s2f(er[qyo[ti][reg] + oh]) + s2f(er[54 + qxo[ti][reg] + ow2]);
                if (kt == 0) bias = (col == 0) ? 0.f : bias;                        // CLS col
                if (q0 == 0 && ti == 0 && reg == 0) bias = (quad == 0) ? 0.f : bias; // CLS row
                bs[reg] = bias;
            }
            bpk[ti][kt][0] = pkhf(bs[0], bs[1]);
            bpk[ti][kt][1] = pkhf(bs[2], bs[3]);
        }
    }

    // fused S2 = log2e*(Q K^T + rel bias); P = exp2(S2) -> overwrites E.
    // K dist-2 register ring; V(0) prefetch issued at kt==11.
    const short* vbase = vt + (long)bh*VROWS*NKPV;
    short8 vf[2][7];
    #pragma unroll
    for (int kt = 0; kt < 13; ++kt) {
        if (kt < 11) {
            #pragma unroll
            for (int c = 0; c < 3; ++c)
                kf[(kt+2)%3][c] = ld8(kbase + ((kt+2)*16 + col)*96 + c*32 + quad*8);
        } else if (kt == 11) {
            #pragma unroll
            for (int nt = 0; nt < 7; ++nt)
                vf[0][nt] = ld8(vbase + (nt*16 + col)*NKPV + quad*8);
        }
        int k = kt*16 + col;
        __builtin_amdgcn_s_setprio(1);
        floatx4 accA = {0.f, 0.f, 0.f, 0.f};
        floatx4 accB = {0.f, 0.f, 0.f, 0.f};
        #pragma unroll
        for (int c = 0; c < 3; ++c) {
            accA = MFMA16(aq[0][c], kf[kt%3][c], accA);
            accB = MFMA16(aq[1][c], kf[kt%3][c], accB);
        }
        __builtin_amdgcn_s_setprio(0);
        unsigned a0 = bpk[0][kt][0], a1 = bpk[0][kt][1];
        unsigned b0 = bpk[1][kt][0], b1 = bpk[1][kt][1];
        smem[0][quad*4 + 0][k] = f2s(__builtin_amdgcn_exp2f(accA[0] + hflo(a0)));
        smem[0][quad*4 + 1][k] = f2s(__builtin_amdgcn_exp2f(accA[1] + hfhi(a0)));
        smem[0][quad*4 + 2][k] = f2s(__builtin_amdgcn_exp2f(accA[2] + hflo(a1)));
        smem[0][quad*4 + 3][k] = f2s(__builtin_amdgcn_exp2f(accA[3] + hfhi(a1)));
        smem[1][quad*4 + 0][k] = f2s(__builtin_amdgcn_exp2f(accB[0] + hflo(b0)));
        smem[1][quad*4 + 1][k] = f2s(__builtin_amdgcn_exp2f(accB[1] + hfhi(b0)));
        smem[1][quad*4 + 2][k] = f2s(__builtin_amdgcn_exp2f(accB[2] + hflo(b1)));
        smem[1][quad*4 + 3][k] = f2s(__builtin_amdgcn_exp2f(accB[3] + hfhi(b1)));
    }
    #pragma unroll
    for (int ti = 0; ti < 2; ++ti)             // zero PV pad cols 208..223
        #pragma unroll
        for (int reg = 0; reg < 4; ++reg)
            smem[ti][quad*4 + reg][208 + col] = 0;

    // O = P V (7 K-chunks of 32; 6 V n-tiles + ones-row n-tile = row sums)
    // V fragments double-buffered: V(c+1) issued before PV-MFMA(c).
    floatx4 o[2][7];
    #pragma unroll
    for (int ti = 0; ti < 2; ++ti)
        #pragma unroll
        for (int nt = 0; nt < 7; ++nt) o[ti][nt] = floatx4{0.f, 0.f, 0.f, 0.f};
    #pragma unroll
    for (int c = 0; c < 7; ++c) {
        if (c < 6) {
            #pragma unroll
            for (int nt = 0; nt < 7; ++nt)
                vf[(c+1)&1][nt] = ld8(vbase + (nt*16 + col)*NKPV + (c+1)*32 + quad*8);
        }
        short8 apA = ld8(&smem[0][col][c*32 + quad*8]);
        short8 apB = ld8(&smem[1][col][c*32 + quad*8]);
        __builtin_amdgcn_s_setprio(1);
        #pragma unroll
        for (int nt = 0; nt < 7; ++nt) {
            o[0][nt] = MFMA16(apA, vf[c&1][nt], o[0][nt]);
            o[1][nt] = MFMA16(apB, vf[c&1][nt], o[1][nt]);
        }
        __builtin_amdgcn_s_setprio(0);
    }

    // epilogue: broadcast row sums, normalize, +residual
    float inv[2][4];
    #pragma unroll
    for (int ti = 0; ti < 2; ++ti)
        #pragma unroll
        for (int reg = 0; reg < 4; ++reg) {
            float srow = __shfl(o[ti][6][reg], lane & 48, 64);
            inv[ti][reg] = 1.0f / srow;
        }
    int b = bh >> 1, h = bh & 1;
    #pragma unroll
    for (int ti = 0; ti < 2; ++ti)
        #pragma unroll
        for (int nt = 0; nt < 6; ++nt) {
            int ch = nt*16 + col;
            #pragma unroll
            for (int reg = 0; reg < 4; ++reg) {
                int q = q0 + ti*16 + quad*4 + reg;
                if (q < NQ) {
                    float val = o[ti][nt][reg] * inv[ti][reg];
                    if (q > 0) val += s2f(qb[((long)bh*NQP + q)*96 + ch]);
                    out[((long)b*NQ + q)*192 + h*96 + ch] = val;
                }
            }
        }
}

// ---------------------------------------------------------------------------
extern "C" void kernel_launch(void* const* d_in, const int* in_sizes, int n_in,
                              void* d_out, int out_size, void* d_ws, size_t ws_size,
                              hipStream_t stream)
{
    const float* hs    = (const float*)d_in[0];
    const float* Wq    = (const float*)d_in[1];
    const float* bq    = (const float*)d_in[2];
    const float* Wk    = (const float*)d_in[3];
    const float* bk    = (const float*)d_in[4];
    const float* Wv    = (const float*)d_in[5];
    const float* bv    = (const float*)d_in[6];
    const float* pqw   = (const float*)d_in[7];
    const float* pkw   = (const float*)d_in[8];
    const float* pvw   = (const float*)d_in[9];
    const float* gq    = (const float*)d_in[10];
    const float* betaq = (const float*)d_in[11];
    const float* gk    = (const float*)d_in[12];
    const float* betak = (const float*)d_in[13];
    const float* gv    = (const float*)d_in[14];
    const float* betav = (const float*)d_in[15];
    const float* relh  = (const float*)d_in[16];
    const float* relw  = (const float*)d_in[17];
    float* out = (float*)d_out;

    // workspace carve (bf16 as short) — ~46.3 MB
    short* pq   = (short*)d_ws;                  // [64][800][96]
    short* pk   = pq  + (long)B_*NQP*CIN;        // [64][208][96]
    short* pv   = pk  + (long)B_*NKP*CIN;        // [64][208][96]
    short* qb   = pv  + (long)B_*NKP*CIN;        // [128][800][96]
    short* kb   = qb  + (long)128*NQP*96;        // [128][208][96]
    short* vt   = kb  + (long)128*NKP*96;        // [128][112][224]
    short* WTq  = vt  + (long)128*VROWS*NKPV;    // [192][96]
    short* WTk  = WTq + 192*96;
    short* WTv  = WTk + 192*96;
    short* relc = WTv + 192*96;                  // [112][96]
    float* cwqT = (float*)(relc + 112*96);       // [9][96] fp32
    float* cwkT = cwqT + 9*96;
    float* cwvT = cwkT + 9*96;

    prep_kernel<<<2829, 256, 0, stream>>>(Wq, Wk, Wv, relh, relw,
                                          pqw, pkw, pvw,
                                          WTq, WTk, WTv, relc, vt,
                                          cwqT, cwkT, cwvT);

    pool_ln_kernel<<<(B_*1008)/16, 256, 0, stream>>>(
        hs, cwqT, cwkT, cwvT, gq, betaq, gk, betak, gv, betav, pq, pk, pv);

    proj_mfma_kernel<<<1216/4, 256, 0, stream>>>(
        pq, pk, pv, WTq, WTk, WTv, bq, bk, bv, qb, kb, vt);

    attn_kernel<<<3200, 64, 0, stream>>>(qb, kb, vt, relc, out);
}

// Round 9
// 233.921 us; speedup vs baseline: 1.0658x; 1.0279x over previous
//
#include <hip/hip_runtime.h>
#include <hip/hip_bf16.h>
#include <hip/hip_fp16.h>

#define B_    64
#define HFS   56
#define CIN   96
#define NQ    785
#define NK    197
#define QW    28
#define KW    14
#define NTOT  3137    // 56*56+1
#define NQP   800     // q tokens padded to 16
#define NKP   208     // kv tokens padded to 16
#define NKPV  224     // PV K-dim padded to 32
#define VROWS 112     // 96 v channels + ones row + 15 zero rows
#define KSCL  0.10206207261596575f   // 96^-0.5, folded into Wk
#define LOG2E 1.4426950408889634f    // exp(x) = exp2(x*log2e), folded into Wk/relc
#define KSCL2 (KSCL*LOG2E)

typedef __attribute__((ext_vector_type(8))) short short8;
typedef __attribute__((ext_vector_type(4))) short shortx4;
typedef __attribute__((ext_vector_type(4))) float floatx4;

__device__ __forceinline__ short f2s(float x) {
    __hip_bfloat16 h = __float2bfloat16(x);
    return *reinterpret_cast<short*>(&h);
}
__device__ __forceinline__ float s2f(short s) {
    __hip_bfloat16 h; *reinterpret_cast<short*>(&h) = s;
    return __bfloat162float(h);
}
__device__ __forceinline__ short8 ld8(const short* p) {
    return *reinterpret_cast<const short8*>(p);
}
__device__ __forceinline__ unsigned pkbf(float a, float b) {
    return (unsigned)(unsigned short)f2s(a) | ((unsigned)(unsigned short)f2s(b) << 16);
}
__device__ __forceinline__ unsigned pkhf(float a, float b) {
    __half2 h = __floats2half2_rn(a, b);
    return *reinterpret_cast<unsigned*>(&h);
}
__device__ __forceinline__ float hflo(unsigned w) {
    __half2 h = *reinterpret_cast<__half2*>(&w);
    return __half2float(__low2half(h));
}
__device__ __forceinline__ float hfhi(unsigned w) {
    __half2 h = *reinterpret_cast<__half2*>(&w);
    return __half2float(__high2half(h));
}

#define MFMA16(a,b,c) __builtin_amdgcn_mfma_f32_16x16x32_bf16((a),(b),(c),0,0,0)

// ---------------------------------------------------------------------------
// Kernel 0: prep = repack W^T (bf16; Wk pre-scaled by 96^-0.5*log2e), rel
// matrix (pre-scaled by log2e), vt pad init, conv-weight transposes.
// ---------------------------------------------------------------------------
__global__ void prep_kernel(const float* __restrict__ Wq, const float* __restrict__ Wk,
                            const float* __restrict__ Wv, const float* __restrict__ relh,
                            const float* __restrict__ relw,
                            const float* __restrict__ pqw, const float* __restrict__ pkw,
                            const float* __restrict__ pvw,
                            short* __restrict__ WTq, short* __restrict__ WTk,
                            short* __restrict__ WTv, short* __restrict__ relc,
                            short* __restrict__ vt,
                            float* __restrict__ cwqT, float* __restrict__ cwkT,
                            float* __restrict__ cwvT)
{
    int i = blockIdx.x * 256 + threadIdx.x;           // 724000 total
    if (i < 18432)      { int o = i/96, c = i%96;              WTq[o*96+c] = f2s(Wq[c*192+o]); }
    else if (i < 36864) { int j = i-18432; int o=j/96,c=j%96;  WTk[o*96+c] = f2s(Wk[c*192+o]*KSCL2); }
    else if (i < 55296) { int j = i-36864; int o=j/96,c=j%96;  WTv[o*96+c] = f2s(Wv[c*192+o]); }
    else if (i < 66048) {
        int j = i - 55296;  int r = j/96, c = j%96;            // 112*96
        float v = (r < 54) ? relh[r*96+c] : ((r < 108) ? relw[(r-54)*96+c] : 0.f);
        relc[r*96+c] = f2s(v*LOG2E);
    } else if (i < 721408) {
        int j2 = i - 66048;                                     // 128 * 5120
        int bh = j2 / 5120, r = j2 % 5120;
        int row, tok; short val;
        if (r < 3584) { row = 96 + r/224; tok = r%224;
                        val = (row == 96 && tok < NK) ? (short)0x3F80 : (short)0; }
        else          { int rr = r-3584; row = rr/16; tok = 208 + (rr%16); val = 0; }
        vt[((long)bh*VROWS + row)*NKPV + tok] = val;
    } else if (i < 724000) {
        int j = i - 721408;                                     // 3 * 864
        int w = j / 864, r = j % 864;
        int c = r / 9, off = r % 9;
        const float* src = (w == 0) ? pqw : (w == 1) ? pkw : pvw;
        float*       dst = (w == 0) ? cwqT : (w == 1) ? cwkT : cwvT;
        dst[off*96 + c] = src[c*9 + off];
    }
}

// ---------------------------------------------------------------------------
// Kernel 1: depthwise 3x3 pool conv + LayerNorm -> bf16 pooled tokens.
// (r8 version, unchanged)
// ---------------------------------------------------------------------------
__device__ __forceinline__ void red16_2(float& s, float& ss) {
    #pragma unroll
    for (int off = 8; off >= 1; off >>= 1) {
        s  += __shfl_xor(s,  off, 16);
        ss += __shfl_xor(ss, off, 16);
    }
}

__device__ __forceinline__ void ln6_store(const float* x, float m, float r,
    const float* __restrict__ g, const float* __restrict__ beta,
    int c0, short* __restrict__ outp)
{
    float2 g0 = *reinterpret_cast<const float2*>(g + c0);
    float2 g1 = *reinterpret_cast<const float2*>(g + c0 + 2);
    float2 g2 = *reinterpret_cast<const float2*>(g + c0 + 4);
    float2 b0 = *reinterpret_cast<const float2*>(beta + c0);
    float2 b1 = *reinterpret_cast<const float2*>(beta + c0 + 2);
    float2 b2 = *reinterpret_cast<const float2*>(beta + c0 + 4);
    unsigned o0 = pkbf((x[0]-m)*r*g0.x + b0.x, (x[1]-m)*r*g0.y + b0.y);
    unsigned o1 = pkbf((x[2]-m)*r*g1.x + b1.x, (x[3]-m)*r*g1.y + b1.y);
    unsigned o2 = pkbf((x[4]-m)*r*g2.x + b2.x, (x[5]-m)*r*g2.y + b2.y);
    *reinterpret_cast<unsigned*>(outp)     = o0;
    *reinterpret_cast<unsigned*>(outp + 2) = o1;
    *reinterpret_cast<unsigned*>(outp + 4) = o2;
}

__device__ __forceinline__ void zero6(short* __restrict__ outp) {
    *reinterpret_cast<unsigned*>(outp)     = 0u;
    *reinterpret_cast<unsigned*>(outp + 2) = 0u;
    *reinterpret_cast<unsigned*>(outp + 4) = 0u;
}

__global__ __launch_bounds__(256) void pool_ln_kernel(
    const float* __restrict__ hs,
    const float* __restrict__ cwqT, const float* __restrict__ cwkT, const float* __restrict__ cwvT,
    const float* __restrict__ gq, const float* __restrict__ betaq,
    const float* __restrict__ gk, const float* __restrict__ betak,
    const float* __restrict__ gv, const float* __restrict__ betav,
    short* __restrict__ pq, short* __restrict__ pk, short* __restrict__ pv)
{
    const int wid  = threadIdx.x >> 6;
    const int lane = threadIdx.x & 63;
    const int sub  = lane >> 4;               // token within wave
    const int li   = lane & 15;               // lane within token group
    const int c0   = li * 6;                  // channels c0..c0+5
    const int gid  = blockIdx.x * 4 + wid;    // 16128 waves total
    const int b    = gid / 252;
    const int slot = gid % 252;               // 200 q-slots + 52 kv-slots
    const long hb  = (long)b * NTOT * CIN;

    if (slot < 200) {                          // ---- q path (stride 2) ----
        int t = slot*4 + sub;
        short* outp = pq + ((long)b*NQP + t)*CIN + c0;
        if (t >= NQ) { zero6(outp); return; }
        float x[6];
        #pragma unroll
        for (int i = 0; i < 6; ++i) x[i] = 0.f;
        if (t == 0) {
            const float* hp = hs + hb + c0;
            float2 a0 = *reinterpret_cast<const float2*>(hp);
            float2 a1 = *reinterpret_cast<const float2*>(hp + 2);
            float2 a2 = *reinterpret_cast<const float2*>(hp + 4);
            x[0]=a0.x; x[1]=a0.y; x[2]=a1.x; x[3]=a1.y; x[4]=a2.x; x[5]=a2.y;
        } else {
            int j = t - 1, oy = j / QW, ox = j % QW;
            float2 hbuf[9][3];
            #pragma unroll
            for (int tap = 0; tap < 9; ++tap) {
                int dy = tap / 3, dx = tap % 3;
                int iy = oy*2 - 1 + dy;
                int ix = ox*2 - 1 + dx;
                if (iy >= 0 && iy < HFS && ix >= 0 && ix < HFS) {
                    const float* hp = hs + hb + (long)(1 + iy*HFS + ix)*CIN + c0;
                    hbuf[tap][0] = *reinterpret_cast<const float2*>(hp);
                    hbuf[tap][1] = *reinterpret_cast<const float2*>(hp + 2);
                    hbuf[tap][2] = *reinterpret_cast<const float2*>(hp + 4);
                } else {
                    hbuf[tap][0] = float2{0.f, 0.f};
                    hbuf[tap][1] = float2{0.f, 0.f};
                    hbuf[tap][2] = float2{0.f, 0.f};
                }
            }
            #pragma unroll
            for (int tap = 0; tap < 9; ++tap) {
                const float* wp = cwqT + tap*96 + c0;
                float2 w0 = *reinterpret_cast<const float2*>(wp);
                float2 w1 = *reinterpret_cast<const float2*>(wp + 2);
                float2 w2 = *reinterpret_cast<const float2*>(wp + 4);
                x[0] = fmaf(hbuf[tap][0].x, w0.x, x[0]); x[1] = fmaf(hbuf[tap][0].y, w0.y, x[1]);
                x[2] = fmaf(hbuf[tap][1].x, w1.x, x[2]); x[3] = fmaf(hbuf[tap][1].y, w1.y, x[3]);
                x[4] = fmaf(hbuf[tap][2].x, w2.x, x[4]); x[5] = fmaf(hbuf[tap][2].y, w2.y, x[5]);
            }
        }
        float s  = (x[0]+x[1]) + (x[2]+x[3]) + (x[4]+x[5]);
        float ss = fmaf(x[0],x[0], fmaf(x[1],x[1], fmaf(x[2],x[2],
                   fmaf(x[3],x[3], fmaf(x[4],x[4], x[5]*x[5])))));
        red16_2(s, ss);
        float m   = s * (1.f/96.f);
        float var = ss * (1.f/96.f) - m*m;
        float r   = rsqrtf(var + 1e-5f);
        ln6_store(x, m, r, gq, betaq, c0, outp);
    } else {                                   // ---- k+v fused (stride 4) ----
        int tok = (slot - 200)*4 + sub;
        short* ok_ = pk + ((long)b*NKP + tok)*CIN + c0;
        short* ov_ = pv + ((long)b*NKP + tok)*CIN + c0;
        if (tok >= NK) { zero6(ok_); zero6(ov_); return; }
        float xk[6], xv[6];
        #pragma unroll
        for (int i = 0; i < 6; ++i) { xk[i] = 0.f; xv[i] = 0.f; }
        if (tok == 0) {
            const float* hp = hs + hb + c0;
            float2 a0 = *reinterpret_cast<const float2*>(hp);
            float2 a1 = *reinterpret_cast<const float2*>(hp + 2);
            float2 a2 = *reinterpret_cast<const float2*>(hp + 4);
            xk[0]=xv[0]=a0.x; xk[1]=xv[1]=a0.y; xk[2]=xv[2]=a1.x;
            xk[3]=xv[3]=a1.y; xk[4]=xv[4]=a2.x; xk[5]=xv[5]=a2.y;
        } else {
            int j = tok - 1, oy = j / KW, ox = j % KW;
            float2 hbuf[9][3];
            #pragma unroll
            for (int tap = 0; tap < 9; ++tap) {
                int dy = tap / 3, dx = tap % 3;
                int iy = oy*4 - 1 + dy;
                int ix = ox*4 - 1 + dx;
                if (iy >= 0 && iy < HFS && ix >= 0 && ix < HFS) {
                    const float* hp = hs + hb + (long)(1 + iy*HFS + ix)*CIN + c0;
                    hbuf[tap][0] = *reinterpret_cast<const float2*>(hp);
                    hbuf[tap][1] = *reinterpret_cast<const float2*>(hp + 2);
                    hbuf[tap][2] = *reinterpret_cast<const float2*>(hp + 4);
                } else {
                    hbuf[tap][0] = float2{0.f, 0.f};
                    hbuf[tap][1] = float2{0.f, 0.f};
                    hbuf[tap][2] = float2{0.f, 0.f};
                }
            }
            #pragma unroll
            for (int tap = 0; tap < 9; ++tap) {
                int wo = tap*96 + c0;
                float2 k0 = *reinterpret_cast<const float2*>(cwkT + wo);
                float2 k1 = *reinterpret_cast<const float2*>(cwkT + wo + 2);
                float2 k2 = *reinterpret_cast<const float2*>(cwkT + wo + 4);
                float2 v0 = *reinterpret_cast<const float2*>(cwvT + wo);
                float2 v1 = *reinterpret_cast<const float2*>(cwvT + wo + 2);
                float2 v2 = *reinterpret_cast<const float2*>(cwvT + wo + 4);
                xk[0] = fmaf(hbuf[tap][0].x, k0.x, xk[0]); xk[1] = fmaf(hbuf[tap][0].y, k0.y, xk[1]);
                xk[2] = fmaf(hbuf[tap][1].x, k1.x, xk[2]); xk[3] = fmaf(hbuf[tap][1].y, k1.y, xk[3]);
                xk[4] = fmaf(hbuf[tap][2].x, k2.x, xk[4]); xk[5] = fmaf(hbuf[tap][2].y, k2.y, xk[5]);
                xv[0] = fmaf(hbuf[tap][0].x, v0.x, xv[0]); xv[1] = fmaf(hbuf[tap][0].y, v0.y, xv[1]);
                xv[2] = fmaf(hbuf[tap][1].x, v1.x, xv[2]); xv[3] = fmaf(hbuf[tap][1].y, v1.y, xv[3]);
                xv[4] = fmaf(hbuf[tap][2].x, v2.x, xv[4]); xv[5] = fmaf(hbuf[tap][2].y, v2.y, xv[5]);
            }
        }
        float sk  = (xk[0]+xk[1]) + (xk[2]+xk[3]) + (xk[4]+xk[5]);
        float ssk = fmaf(xk[0],xk[0], fmaf(xk[1],xk[1], fmaf(xk[2],xk[2],
                    fmaf(xk[3],xk[3], fmaf(xk[4],xk[4], xk[5]*xk[5])))));
        float sv  = (xv[0]+xv[1]) + (xv[2]+xv[3]) + (xv[4]+xv[5]);
        float ssv = fmaf(xv[0],xv[0], fmaf(xv[1],xv[1], fmaf(xv[2],xv[2],
                    fmaf(xv[3],xv[3], fmaf(xv[4],xv[4], xv[5]*xv[5])))));
        red16_2(sk, ssk);
        red16_2(sv, ssv);
        float mk = sk * (1.f/96.f), vark = ssk * (1.f/96.f) - mk*mk;
        float mv = sv * (1.f/96.f), varv = ssv * (1.f/96.f) - mv*mv;
        float rk = rsqrtf(vark + 1e-5f);
        float rv = rsqrtf(varv + 1e-5f);
        ln6_store(xk, mk, rk, gk, betak, c0, ok_);
        ln6_store(xv, mv, rv, gv, betav, c0, ov_);
    }
}

// ---------------------------------------------------------------------------
// Kernel 2: projections as MFMA GEMM. FOUR 16-token tiles per wave (r8).
// ---------------------------------------------------------------------------
__global__ __launch_bounds__(256) void proj_mfma_kernel(
    const short* __restrict__ pq, const short* __restrict__ pk, const short* __restrict__ pv,
    const short* __restrict__ WTq, const short* __restrict__ WTk, const short* __restrict__ WTv,
    const float* __restrict__ bq, const float* __restrict__ bk, const float* __restrict__ bv,
    short* __restrict__ qb, short* __restrict__ kb, short* __restrict__ vt)
{
    int wid  = threadIdx.x >> 6;
    int lane = threadIdx.x & 63;
    int quad = lane >> 4, col = lane & 15;
    int wt = blockIdx.x * 4 + wid;              // 1216 wave-units total

    if (wt < 1008) {                            // ---- q and k: swapped ----
        const short *A, *WT; const float* bias; short* outp;
        int ntokp, row0; float bsc;
        if (wt < 800) { A = pq; WT = WTq; bias = bq; outp = qb; ntokp = NQP; row0 = wt*64; bsc = 1.f; }
        else          { A = pk; WT = WTk; bias = bk; outp = kb; ntokp = NKP; row0 = (wt-800)*64; bsc = KSCL2; }

        short8 bt[4][3];
        #pragma unroll
        for (int ti = 0; ti < 4; ++ti)
            #pragma unroll
            for (int cc = 0; cc < 3; ++cc)
                bt[ti][cc] = ld8(A + (long)(row0 + ti*16 + col)*96 + cc*32 + quad*8);

        int bT[4], tokT[4];
        #pragma unroll
        for (int ti = 0; ti < 4; ++ti) {
            int r = row0 + ti*16;
            bT[ti] = r / ntokp;
            tokT[ti] = (r % ntokp) + col;
        }

        short8 af[2][3];
        #pragma unroll
        for (int cc = 0; cc < 3; ++cc)
            af[0][cc] = ld8(WT + col*96 + cc*32 + quad*8);

        #pragma unroll
        for (int nt = 0; nt < 12; ++nt) {
            if (nt < 11) {
                #pragma unroll
                for (int cc = 0; cc < 3; ++cc)
                    af[(nt+1)&1][cc] = ld8(WT + ((nt+1)*16 + col)*96 + cc*32 + quad*8);
            }
            int o0 = nt*16 + quad*4;            // 4 consecutive outputs
            float4 bo = *reinterpret_cast<const float4*>(bias + o0);
            int h  = (o0 >= 96) ? 1 : 0;
            int d0 = o0 - h*96;
            #pragma unroll
            for (int ti = 0; ti < 4; ++ti) {
                floatx4 acc = {0.f, 0.f, 0.f, 0.f};
                #pragma unroll
                for (int cc = 0; cc < 3; ++cc)
                    acc = MFMA16(af[nt&1][cc], bt[ti][cc], acc);
                shortx4 val;
                val.x = f2s(acc[0] + bo.x*bsc);
                val.y = f2s(acc[1] + bo.y*bsc);
                val.z = f2s(acc[2] + bo.z*bsc);
                val.w = f2s(acc[3] + bo.w*bsc);
                *reinterpret_cast<shortx4*>(outp + ((long)(bT[ti]*2 + h)*ntokp + tokT[ti])*96 + d0) = val;
            }
        }
    } else {                                    // ---- v: original orient ----
        int row0 = (wt - 1008) * 64;
        short8 at[4][3];
        #pragma unroll
        for (int ti = 0; ti < 4; ++ti)
            #pragma unroll
            for (int cc = 0; cc < 3; ++cc)
                at[ti][cc] = ld8(pv + (long)(row0 + ti*16 + col)*96 + cc*32 + quad*8);

        int bT[4], t0T[4];
        #pragma unroll
        for (int ti = 0; ti < 4; ++ti) {
            int r = row0 + ti*16;
            bT[ti] = r / NKP;
            t0T[ti] = (r % NKP) + quad*4;       // 4 consecutive tokens
        }

        short8 bf[2][3];
        #pragma unroll
        for (int cc = 0; cc < 3; ++cc)
            bf[0][cc] = ld8(WTv + col*96 + cc*32 + quad*8);

        #pragma unroll
        for (int nt = 0; nt < 12; ++nt) {
            if (nt < 11) {
                #pragma unroll
                for (int cc = 0; cc < 3; ++cc)
                    bf[(nt+1)&1][cc] = ld8(WTv + ((nt+1)*16 + col)*96 + cc*32 + quad*8);
            }
            int o = nt*16 + col;
            int h = (o >= 96) ? 1 : 0;
            int d = o - h*96;
            float bo = bv[o];
            #pragma unroll
            for (int ti = 0; ti < 4; ++ti) {
                floatx4 acc = {0.f, 0.f, 0.f, 0.f};
                #pragma unroll
                for (int cc = 0; cc < 3; ++cc)
                    acc = MFMA16(at[ti][cc], bf[nt&1][cc], acc);
                shortx4 val;
                val.x = (t0T[ti]+0 < NK) ? f2s(acc[0] + bo) : (short)0;
                val.y = (t0T[ti]+1 < NK) ? f2s(acc[1] + bo) : (short)0;
                val.z = (t0T[ti]+2 < NK) ? f2s(acc[2] + bo) : (short)0;
                val.w = (t0T[ti]+3 < NK) ? f2s(acc[3] + bo) : (short)0;
                *reinterpret_cast<shortx4*>(vt + ((long)(bT[ti]*2 + h)*VROWS + d)*NKPV + t0T[ti]) = val;
            }
        }
    }
}

// ---------------------------------------------------------------------------
// Kernel 3: MFMA attention (r6 structure). ONE wave per block, TWO 16-q-row
// tiles per wave, streamed K/V from L2, K dist-2 ring.
// NEW vs r8: vectorized epilogue — o*inv staged into the dead P-LDS as f32
// (stride 102 dwords, 2-way banks = free), then 2 lanes/row handle 48
// contiguous channels each: 6x16B residual loads + 12x16B stores per lane
// replace 48 scalar 2B loads + 48 scalar 4B stores.
// ---------------------------------------------------------------------------
__global__ __launch_bounds__(64, 2) void attn_kernel(
    const short* __restrict__ qb, const short* __restrict__ kb,
    const short* __restrict__ vt, const short* __restrict__ relc,
    float* __restrict__ out)
{
    __shared__ __align__(16) short smem[2][16][232];   // 14848 B

    int lane = threadIdx.x & 63;
    int quad = lane >> 4, col = lane & 15;

    int bid = blockIdx.x;                      // 3200 = 8 * 400
    int wt  = (bid & 7) * 400 + (bid >> 3);    // XCD-contiguous ranges (25 waves/bh)
    int bh  = wt / 25;
    int tp  = wt % 25;
    int q0  = tp * 32;                         // rows q0..q0+31

    // Q A-fragments for both tiles
    const short* qrow = qb + ((long)bh*NQP + q0)*96;
    short8 aq[2][3];
    #pragma unroll
    for (int ti = 0; ti < 2; ++ti)
        #pragma unroll
        for (int c = 0; c < 3; ++c)
            aq[ti][c] = ld8(qrow + (ti*16 + col)*96 + c*32 + quad*8);

    // E = Q Rel^T with rel-fragment register double-buffer
    short8 rf[2][3];
    #pragma unroll
    for (int c = 0; c < 3; ++c)
        rf[0][c] = ld8(relc + col*96 + c*32 + quad*8);
    #pragma unroll
    for (int rt = 0; rt < 7; ++rt) {
        if (rt < 6) {
            #pragma unroll
            for (int c = 0; c < 3; ++c)
                rf[(rt+1)&1][c] = ld8(relc + ((rt+1)*16 + col)*96 + c*32 + quad*8);
        }
        #pragma unroll
        for (int ti = 0; ti < 2; ++ti) {
            floatx4 acc = {0.f, 0.f, 0.f, 0.f};
            #pragma unroll
            for (int c = 0; c < 3; ++c)
                acc = MFMA16(aq[ti][c], rf[rt&1][c], acc);
            #pragma unroll
            for (int reg = 0; reg < 4; ++reg)
                smem[ti][quad*4 + reg][rt*16 + col] = f2s(acc[reg]);
        }
    }

    // issue K(0) and K(1) loads now — latency hides under the bias gather
    const short* kbase = kb + (long)bh*NKP*96;
    short8 kf[3][3];
    #pragma unroll
    for (int c = 0; c < 3; ++c)
        kf[0][c] = ld8(kbase + col*96 + c*32 + quad*8);
    #pragma unroll
    for (int c = 0; c < 3; ++c)
        kf[1][c] = ld8(kbase + (16 + col)*96 + c*32 + quad*8);

    // per-row q spatial coords (8 rows per lane: 2 tiles x 4 regs)
    int qyo[2][4], qxo[2][4];
    #pragma unroll
    for (int ti = 0; ti < 2; ++ti)
        #pragma unroll
        for (int reg = 0; reg < 4; ++reg) {
            int qq = q0 + ti*16 + quad*4 + reg;
            int jj = (qq > 0) ? (qq - 1) : 0;
            qyo[ti][reg] = jj / QW;
            qxo[ti][reg] = jj % QW;
        }

    // hoisted rel-bias gather: 13 kt x 8 rows -> 52 packed-f16 regs
    unsigned bpk[2][13][2];
    #pragma unroll
    for (int kt = 0; kt < 13; ++kt) {
        int k  = kt*16 + col;
        int kk = (k > 0) ? (k - 1) : 0;
        int ky = kk / 14;  ky = (ky < 13) ? ky : 13;
        int kx = kk - 14*ky;
        int oh  = 26 - 2*ky;
        int ow2 = 26 - 2*kx;
        #pragma unroll
        for (int ti = 0; ti < 2; ++ti) {
            float bs[4];
            #pragma unroll
            for (int reg = 0; reg < 4; ++reg) {
                const short* er = &smem[ti][quad*4 + reg][0];
                float bias = s2f(er[qyo[ti][reg] + oh]) + s2f(er[54 + qxo[ti][reg] + ow2]);
                if (kt == 0) bias = (col == 0) ? 0.f : bias;                        // CLS col
                if (q0 == 0 && ti == 0 && reg == 0) bias = (quad == 0) ? 0.f : bias; // CLS row
                bs[reg] = bias;
            }
            bpk[ti][kt][0] = pkhf(bs[0], bs[1]);
            bpk[ti][kt][1] = pkhf(bs[2], bs[3]);
        }
    }

    // fused S2 = log2e*(Q K^T + rel bias); P = exp2(S2) -> overwrites E.
    // K dist-2 register ring; V(0) prefetch issued at kt==11.
    const short* vbase = vt + (long)bh*VROWS*NKPV;
    short8 vf[2][7];
    #pragma unroll
    for (int kt = 0; kt < 13; ++kt) {
        if (kt < 11) {
            #pragma unroll
            for (int c = 0; c < 3; ++c)
                kf[(kt+2)%3][c] = ld8(kbase + ((kt+2)*16 + col)*96 + c*32 + quad*8);
        } else if (kt == 11) {
            #pragma unroll
            for (int nt = 0; nt < 7; ++nt)
                vf[0][nt] = ld8(vbase + (nt*16 + col)*NKPV + quad*8);
        }
        int k = kt*16 + col;
        __builtin_amdgcn_s_setprio(1);
        floatx4 accA = {0.f, 0.f, 0.f, 0.f};
        floatx4 accB = {0.f, 0.f, 0.f, 0.f};
        #pragma unroll
        for (int c = 0; c < 3; ++c) {
            accA = MFMA16(aq[0][c], kf[kt%3][c], accA);
            accB = MFMA16(aq[1][c], kf[kt%3][c], accB);
        }
        __builtin_amdgcn_s_setprio(0);
        unsigned a0 = bpk[0][kt][0], a1 = bpk[0][kt][1];
        unsigned b0 = bpk[1][kt][0], b1 = bpk[1][kt][1];
        smem[0][quad*4 + 0][k] = f2s(__builtin_amdgcn_exp2f(accA[0] + hflo(a0)));
        smem[0][quad*4 + 1][k] = f2s(__builtin_amdgcn_exp2f(accA[1] + hfhi(a0)));
        smem[0][quad*4 + 2][k] = f2s(__builtin_amdgcn_exp2f(accA[2] + hflo(a1)));
        smem[0][quad*4 + 3][k] = f2s(__builtin_amdgcn_exp2f(accA[3] + hfhi(a1)));
        smem[1][quad*4 + 0][k] = f2s(__builtin_amdgcn_exp2f(accB[0] + hflo(b0)));
        smem[1][quad*4 + 1][k] = f2s(__builtin_amdgcn_exp2f(accB[1] + hfhi(b0)));
        smem[1][quad*4 + 2][k] = f2s(__builtin_amdgcn_exp2f(accB[2] + hflo(b1)));
        smem[1][quad*4 + 3][k] = f2s(__builtin_amdgcn_exp2f(accB[3] + hfhi(b1)));
    }
    #pragma unroll
    for (int ti = 0; ti < 2; ++ti)             // zero PV pad cols 208..223
        #pragma unroll
        for (int reg = 0; reg < 4; ++reg)
            smem[ti][quad*4 + reg][208 + col] = 0;

    // O = P V (7 K-chunks of 32; 6 V n-tiles + ones-row n-tile = row sums)
    // V fragments double-buffered: V(c+1) issued before PV-MFMA(c).
    floatx4 o[2][7];
    #pragma unroll
    for (int ti = 0; ti < 2; ++ti)
        #pragma unroll
        for (int nt = 0; nt < 7; ++nt) o[ti][nt] = floatx4{0.f, 0.f, 0.f, 0.f};
    #pragma unroll
    for (int c = 0; c < 7; ++c) {
        if (c < 6) {
            #pragma unroll
            for (int nt = 0; nt < 7; ++nt)
                vf[(c+1)&1][nt] = ld8(vbase + (nt*16 + col)*NKPV + (c+1)*32 + quad*8);
        }
        short8 apA = ld8(&smem[0][col][c*32 + quad*8]);
        short8 apB = ld8(&smem[1][col][c*32 + quad*8]);
        __builtin_amdgcn_s_setprio(1);
        #pragma unroll
        for (int nt = 0; nt < 7; ++nt) {
            o[0][nt] = MFMA16(apA, vf[c&1][nt], o[0][nt]);
            o[1][nt] = MFMA16(apB, vf[c&1][nt], o[1][nt]);
        }
        __builtin_amdgcn_s_setprio(0);
    }

    // broadcast row sums
    float inv[2][4];
    #pragma unroll
    for (int ti = 0; ti < 2; ++ti)
        #pragma unroll
        for (int reg = 0; reg < 4; ++reg) {
            float srow = __shfl(o[ti][6][reg], lane & 48, 64);
            inv[ti][reg] = 1.0f / srow;
        }

    // epilogue: stage o*inv into dead P-LDS as f32 [2][16][stride 102],
    // then 2 lanes per row emit 48 contiguous channels (vectorized I/O).
    float* fsm = reinterpret_cast<float*>(&smem[0][0][0]);
    #pragma unroll
    for (int ti = 0; ti < 2; ++ti)
        #pragma unroll
        for (int nt = 0; nt < 6; ++nt)
            #pragma unroll
            for (int reg = 0; reg < 4; ++reg)
                fsm[(ti*16 + quad*4 + reg)*102 + nt*16 + col] = o[ti][nt][reg] * inv[ti][reg];

    int b = bh >> 1, h = bh & 1;
    int r2  = lane >> 1;                       // 0..31: row across both tiles
    int h2  = lane & 1;                        // half-row
    int ti2 = r2 >> 4, row2 = r2 & 15;
    int q   = q0 + ti2*16 + row2;
    int ch0 = h2 * 48;
    if (q < NQ) {
        const float* src  = fsm + (ti2*16 + row2)*102 + ch0;
        const short* resp = qb + ((long)bh*NQP + q)*96 + ch0;
        float*       outp = out + ((long)b*NQ + q)*192 + h*96 + ch0;
        #pragma unroll
        for (int i = 0; i < 6; ++i) {
            float2 v0 = *reinterpret_cast<const float2*>(src + i*8 + 0);
            float2 v1 = *reinterpret_cast<const float2*>(src + i*8 + 2);
            float2 v2 = *reinterpret_cast<const float2*>(src + i*8 + 4);
            float2 v3 = *reinterpret_cast<const float2*>(src + i*8 + 6);
            float r_[8];
            if (q > 0) {
                short8 rs = ld8(resp + i*8);
                #pragma unroll
                for (int j = 0; j < 8; ++j) r_[j] = s2f(rs[j]);
            } else {
                #pragma unroll
                for (int j = 0; j < 8; ++j) r_[j] = 0.f;
            }
            float4 o0, o1;
            o0.x = v0.x + r_[0]; o0.y = v0.y + r_[1];
            o0.z = v1.x + r_[2]; o0.w = v1.y + r_[3];
            o1.x = v2.x + r_[4]; o1.y = v2.y + r_[5];
            o1.z = v3.x + r_[6]; o1.w = v3.y + r_[7];
            *reinterpret_cast<float4*>(outp + i*8)     = o0;
            *reinterpret_cast<float4*>(outp + i*8 + 4) = o1;
        }
    }
}

// ---------------------------------------------------------------------------
extern "C" void kernel_launch(void* const* d_in, const int* in_sizes, int n_in,
                              void* d_out, int out_size, void* d_ws, size_t ws_size,
                              hipStream_t stream)
{
    const float* hs    = (const float*)d_in[0];
    const float* Wq    = (const float*)d_in[1];
    const float* bq    = (const float*)d_in[2];
    const float* Wk    = (const float*)d_in[3];
    const float* bk    = (const float*)d_in[4];
    const float* Wv    = (const float*)d_in[5];
    const float* bv    = (const float*)d_in[6];
    const float* pqw   = (const float*)d_in[7];
    const float* pkw   = (const float*)d_in[8];
    const float* pvw   = (const float*)d_in[9];
    const float* gq    = (const float*)d_in[10];
    const float* betaq = (const float*)d_in[11];
    const float* gk    = (const float*)d_in[12];
    const float* betak = (const float*)d_in[13];
    const float* gv    = (const float*)d_in[14];
    const float* betav = (const float*)d_in[15];
    const float* relh  = (const float*)d_in[16];
    const float* relw  = (const float*)d_in[17];
    float* out = (float*)d_out;

    // workspace carve (bf16 as short) — ~46.3 MB
    short* pq   = (short*)d_ws;                  // [64][800][96]
    short* pk   = pq  + (long)B_*NQP*CIN;        // [64][208][96]
    short* pv   = pk  + (long)B_*NKP*CIN;        // [64][208][96]
    short* qb   = pv  + (long)B_*NKP*CIN;        // [128][800][96]
    short* kb   = qb  + (long)128*NQP*96;        // [128][208][96]
    short* vt   = kb  + (long)128*NKP*96;        // [128][112][224]
    short* WTq  = vt  + (long)128*VROWS*NKPV;    // [192][96]
    short* WTk  = WTq + 192*96;
    short* WTv  = WTk + 192*96;
    short* relc = WTv + 192*96;                  // [112][96]
    float* cwqT = (float*)(relc + 112*96);       // [9][96] fp32
    float* cwkT = cwqT + 9*96;
    float* cwvT = cwkT + 9*96;

    prep_kernel<<<2829, 256, 0, stream>>>(Wq, Wk, Wv, relh, relw,
                                          pqw, pkw, pvw,
                                          WTq, WTk, WTv, relc, vt,
                                          cwqT, cwkT, cwvT);

    pool_ln_kernel<<<(B_*1008)/16, 256, 0, stream>>>(
        hs, cwqT, cwkT, cwvT, gq, betaq, gk, betak, gv, betav, pq, pk, pv);

    proj_mfma_kernel<<<1216/4, 256, 0, stream>>>(
        pq, pk, pv, WTq, WTk, WTv, bq, bk, bv, qb, kb, vt);

    attn_kernel<<<3200, 64, 0, stream>>>(qb, kb, vt, relc, out);
}

// Round 10
// 231.165 us; speedup vs baseline: 1.0785x; 1.0119x over previous
//
#include <hip/hip_runtime.h>
#include <hip/hip_bf16.h>
#include <hip/hip_fp16.h>

#define B_    64
#define HFS   56
#define CIN   96
#define NQ    785
#define NK    197
#define QW    28
#define KW    14
#define NTOT  3137    // 56*56+1
#define NQP   800     // q tokens padded to 16
#define NKP   208     // kv tokens padded to 16
#define NKPV  224     // PV K-dim padded to 32
#define VROWS 112     // 96 v channels + ones row + 15 zero rows
#define KSCL  0.10206207261596575f   // 96^-0.5, folded into Wk
#define LOG2E 1.4426950408889634f    // exp(x) = exp2(x*log2e), folded into Wk/relc
#define KSCL2 (KSCL*LOG2E)

typedef __attribute__((ext_vector_type(8))) short short8;
typedef __attribute__((ext_vector_type(4))) short shortx4;
typedef __attribute__((ext_vector_type(4))) float floatx4;
typedef __attribute__((ext_vector_type(4))) unsigned uintx4;

__device__ __forceinline__ short f2s(float x) {
    __hip_bfloat16 h = __float2bfloat16(x);
    return *reinterpret_cast<short*>(&h);
}
__device__ __forceinline__ float s2f(short s) {
    __hip_bfloat16 h; *reinterpret_cast<short*>(&h) = s;
    return __bfloat162float(h);
}
__device__ __forceinline__ short8 ld8(const short* p) {
    return *reinterpret_cast<const short8*>(p);
}
__device__ __forceinline__ unsigned pkbf(float a, float b) {
    return (unsigned)(unsigned short)f2s(a) | ((unsigned)(unsigned short)f2s(b) << 16);
}
__device__ __forceinline__ unsigned pkhf(float a, float b) {
    __half2 h = __floats2half2_rn(a, b);
    return *reinterpret_cast<unsigned*>(&h);
}
__device__ __forceinline__ float hflo(unsigned w) {
    __half2 h = *reinterpret_cast<__half2*>(&w);
    return __half2float(__low2half(h));
}
__device__ __forceinline__ float hfhi(unsigned w) {
    __half2 h = *reinterpret_cast<__half2*>(&w);
    return __half2float(__high2half(h));
}

#define MFMA16(a,b,c) __builtin_amdgcn_mfma_f32_16x16x32_bf16((a),(b),(c),0,0,0)

// ---------------------------------------------------------------------------
// Kernel 0 (tiny): conv-weight transposes only — the sole dependency of the
// pool phase. Everything else from old prep now rides inside pool's grid.
// ---------------------------------------------------------------------------
__global__ void prep_w_kernel(const float* __restrict__ pqw, const float* __restrict__ pkw,
                              const float* __restrict__ pvw,
                              float* __restrict__ cwqT, float* __restrict__ cwkT,
                              float* __restrict__ cwvT)
{
    int i = blockIdx.x * 256 + threadIdx.x;            // 2592 items
    if (i < 2592) {
        int w = i / 864, r = i % 864;
        int c = r / 9, off = r % 9;
        const float* src = (w == 0) ? pqw : (w == 1) ? pkw : pvw;
        float*       dst = (w == 0) ? cwqT : (w == 1) ? cwkT : cwvT;
        dst[off*96 + c] = src[c*9 + off];
    }
}

// ---------------------------------------------------------------------------
// Kernel 1: pool conv + LN (12 lanes x 8 ch, float4 loads: 36 load-instrs
// per token instead of 54 — L1-request-rate fix) PLUS prep-rest blocks
// (WT repack / relc / vt pad-init vectorized) appended to the same grid.
// Pool blocks: 0..4031. Prep blocks: 4032..4609 (148k items, no data flow
// with pool -> no sync needed; completes before kernel end gates proj/attn).
// ---------------------------------------------------------------------------
__device__ __forceinline__ void red16_2(float& s, float& ss) {
    #pragma unroll
    for (int off = 8; off >= 1; off >>= 1) {
        s  += __shfl_xor(s,  off, 16);
        ss += __shfl_xor(ss, off, 16);
    }
}

__device__ __forceinline__ void ln8_store(const float* x, float m, float r,
    const float* __restrict__ g, const float* __restrict__ beta,
    int c0, short* __restrict__ outp)
{
    float4 g0 = *reinterpret_cast<const float4*>(g + c0);
    float4 g1 = *reinterpret_cast<const float4*>(g + c0 + 4);
    float4 b0 = *reinterpret_cast<const float4*>(beta + c0);
    float4 b1 = *reinterpret_cast<const float4*>(beta + c0 + 4);
    uintx4 v;
    v.x = pkbf((x[0]-m)*r*g0.x + b0.x, (x[1]-m)*r*g0.y + b0.y);
    v.y = pkbf((x[2]-m)*r*g0.z + b0.z, (x[3]-m)*r*g0.w + b0.w);
    v.z = pkbf((x[4]-m)*r*g1.x + b1.x, (x[5]-m)*r*g1.y + b1.y);
    v.w = pkbf((x[6]-m)*r*g1.z + b1.z, (x[7]-m)*r*g1.w + b1.w);
    *reinterpret_cast<uintx4*>(outp + c0) = v;
}

__device__ __forceinline__ void zero8(short* __restrict__ outp, int c0) {
    uintx4 v = {0u, 0u, 0u, 0u};
    *reinterpret_cast<uintx4*>(outp + c0) = v;
}

__global__ __launch_bounds__(256) void pool_ln_kernel(
    const float* __restrict__ hs,
    const float* __restrict__ cwqT, const float* __restrict__ cwkT, const float* __restrict__ cwvT,
    const float* __restrict__ gq, const float* __restrict__ betaq,
    const float* __restrict__ gk, const float* __restrict__ betak,
    const float* __restrict__ gv, const float* __restrict__ betav,
    short* __restrict__ pq, short* __restrict__ pk, short* __restrict__ pv,
    const float* __restrict__ Wq, const float* __restrict__ Wk, const float* __restrict__ Wv,
    const float* __restrict__ relh, const float* __restrict__ relw,
    short* __restrict__ WTq, short* __restrict__ WTk, short* __restrict__ WTv,
    short* __restrict__ relc, short* __restrict__ vt)
{
    // ---------------- prep-rest blocks ----------------
    if (blockIdx.x >= 4032) {
        int i = (blockIdx.x - 4032) * 256 + threadIdx.x;   // 147968 items
        if (i < 18432)      { int o = i/96, c = i%96;              WTq[o*96+c] = f2s(Wq[c*192+o]); }
        else if (i < 36864) { int j = i-18432; int o=j/96,c=j%96;  WTk[o*96+c] = f2s(Wk[c*192+o]*KSCL2); }
        else if (i < 55296) { int j = i-36864; int o=j/96,c=j%96;  WTv[o*96+c] = f2s(Wv[c*192+o]); }
        else if (i < 66048) {
            int j = i - 55296;  int r = j/96, c = j%96;            // 112*96
            float v = (r < 54) ? relh[r*96+c] : ((r < 108) ? relw[(r-54)*96+c] : 0.f);
            relc[r*96+c] = f2s(v*LOG2E);
        } else {
            int j2 = i - 66048;                                     // 128 bh * 640 vec8
            int bh = j2 / 640, r = (j2 % 640) * 8;
            short8 val = {0,0,0,0,0,0,0,0};
            long addr;
            if (r < 3584) {                                         // rows 96..111, all 224 cols
                int row = 96 + r/224, tok0 = r%224;
                if (row == 96) {
                    #pragma unroll
                    for (int t = 0; t < 8; ++t)
                        val[t] = (tok0 + t < NK) ? (short)0x3F80 : (short)0;
                }
                addr = ((long)bh*VROWS + row)*NKPV + tok0;
            } else {                                                // rows 0..95, cols 208..223
                int rr = r - 3584;
                int row = rr/16, tok0 = 208 + (rr%16);
                addr = ((long)bh*VROWS + row)*NKPV + tok0;
            }
            *reinterpret_cast<short8*>(vt + addr) = val;
        }
        return;
    }

    // ---------------- pool blocks ----------------
    const int wid  = threadIdx.x >> 6;
    const int lane = threadIdx.x & 63;
    const int sub  = lane >> 4;               // token within wave
    const int li   = lane & 15;               // lane within token group
    const bool ACT = (li < 12);               // 12 lanes x 8 channels = 96
    const int c0   = li * 8;                  // channels c0..c0+7 (ACT only)
    const int gid  = blockIdx.x * 4 + wid;    // 16128 pool waves
    const int b    = gid / 252;
    const int slot = gid % 252;               // 200 q-slots + 52 kv-slots
    const long hb  = (long)b * NTOT * CIN;

    if (slot < 200) {                          // ---- q path (stride 2) ----
        int t = slot*4 + sub;
        short* outp = pq + ((long)b*NQP + t)*CIN;
        if (t >= NQ) { if (ACT) zero8(outp, c0); return; }
        float x[8];
        #pragma unroll
        for (int i = 0; i < 8; ++i) x[i] = 0.f;
        if (ACT) {
            if (t == 0) {
                float4 a0 = *reinterpret_cast<const float4*>(hs + hb + c0);
                float4 a1 = *reinterpret_cast<const float4*>(hs + hb + c0 + 4);
                x[0]=a0.x; x[1]=a0.y; x[2]=a0.z; x[3]=a0.w;
                x[4]=a1.x; x[5]=a1.y; x[6]=a1.z; x[7]=a1.w;
            } else {
                int j = t - 1, oy = j / QW, ox = j % QW;
                float4 hbuf[9][2];
                #pragma unroll
                for (int tap = 0; tap < 9; ++tap) {
                    int dy = tap / 3, dx = tap % 3;
                    int iy = oy*2 - 1 + dy;
                    int ix = ox*2 - 1 + dx;
                    if (iy >= 0 && iy < HFS && ix >= 0 && ix < HFS) {
                        const float* hp = hs + hb + (long)(1 + iy*HFS + ix)*CIN + c0;
                        hbuf[tap][0] = *reinterpret_cast<const float4*>(hp);
                        hbuf[tap][1] = *reinterpret_cast<const float4*>(hp + 4);
                    } else {
                        hbuf[tap][0] = float4{0.f,0.f,0.f,0.f};
                        hbuf[tap][1] = float4{0.f,0.f,0.f,0.f};
                    }
                }
                #pragma unroll
                for (int tap = 0; tap < 9; ++tap) {
                    float4 w0 = *reinterpret_cast<const float4*>(cwqT + tap*96 + c0);
                    float4 w1 = *reinterpret_cast<const float4*>(cwqT + tap*96 + c0 + 4);
                    x[0] = fmaf(hbuf[tap][0].x, w0.x, x[0]); x[1] = fmaf(hbuf[tap][0].y, w0.y, x[1]);
                    x[2] = fmaf(hbuf[tap][0].z, w0.z, x[2]); x[3] = fmaf(hbuf[tap][0].w, w0.w, x[3]);
                    x[4] = fmaf(hbuf[tap][1].x, w1.x, x[4]); x[5] = fmaf(hbuf[tap][1].y, w1.y, x[5]);
                    x[6] = fmaf(hbuf[tap][1].z, w1.z, x[6]); x[7] = fmaf(hbuf[tap][1].w, w1.w, x[7]);
                }
            }
        }
        float s  = ((x[0]+x[1]) + (x[2]+x[3])) + ((x[4]+x[5]) + (x[6]+x[7]));
        float ss = fmaf(x[0],x[0], fmaf(x[1],x[1], fmaf(x[2],x[2], fmaf(x[3],x[3],
                   fmaf(x[4],x[4], fmaf(x[5],x[5], fmaf(x[6],x[6], x[7]*x[7])))))));
        red16_2(s, ss);
        float m   = s * (1.f/96.f);
        float var = ss * (1.f/96.f) - m*m;
        float r   = rsqrtf(var + 1e-5f);
        if (ACT) ln8_store(x, m, r, gq, betaq, c0, outp);
    } else {                                   // ---- k+v fused (stride 4) ----
        int tok = (slot - 200)*4 + sub;
        short* ok_ = pk + ((long)b*NKP + tok)*CIN;
        short* ov_ = pv + ((long)b*NKP + tok)*CIN;
        if (tok >= NK) { if (ACT) { zero8(ok_, c0); zero8(ov_, c0); } return; }
        float xk[8], xv[8];
        #pragma unroll
        for (int i = 0; i < 8; ++i) { xk[i] = 0.f; xv[i] = 0.f; }
        if (ACT) {
            if (tok == 0) {
                float4 a0 = *reinterpret_cast<const float4*>(hs + hb + c0);
                float4 a1 = *reinterpret_cast<const float4*>(hs + hb + c0 + 4);
                xk[0]=xv[0]=a0.x; xk[1]=xv[1]=a0.y; xk[2]=xv[2]=a0.z; xk[3]=xv[3]=a0.w;
                xk[4]=xv[4]=a1.x; xk[5]=xv[5]=a1.y; xk[6]=xv[6]=a1.z; xk[7]=xv[7]=a1.w;
            } else {
                int j = tok - 1, oy = j / KW, ox = j % KW;
                float4 hbuf[9][2];
                #pragma unroll
                for (int tap = 0; tap < 9; ++tap) {
                    int dy = tap / 3, dx = tap % 3;
                    int iy = oy*4 - 1 + dy;
                    int ix = ox*4 - 1 + dx;
                    if (iy >= 0 && iy < HFS && ix >= 0 && ix < HFS) {
                        const float* hp = hs + hb + (long)(1 + iy*HFS + ix)*CIN + c0;
                        hbuf[tap][0] = *reinterpret_cast<const float4*>(hp);
                        hbuf[tap][1] = *reinterpret_cast<const float4*>(hp + 4);
                    } else {
                        hbuf[tap][0] = float4{0.f,0.f,0.f,0.f};
                        hbuf[tap][1] = float4{0.f,0.f,0.f,0.f};
                    }
                }
                #pragma unroll
                for (int tap = 0; tap < 9; ++tap) {
                    int wo = tap*96 + c0;
                    float4 k0 = *reinterpret_cast<const float4*>(cwkT + wo);
                    float4 k1 = *reinterpret_cast<const float4*>(cwkT + wo + 4);
                    float4 v0 = *reinterpret_cast<const float4*>(cwvT + wo);
                    float4 v1 = *reinterpret_cast<const float4*>(cwvT + wo + 4);
                    xk[0] = fmaf(hbuf[tap][0].x, k0.x, xk[0]); xk[1] = fmaf(hbuf[tap][0].y, k0.y, xk[1]);
                    xk[2] = fmaf(hbuf[tap][0].z, k0.z, xk[2]); xk[3] = fmaf(hbuf[tap][0].w, k0.w, xk[3]);
                    xk[4] = fmaf(hbuf[tap][1].x, k1.x, xk[4]); xk[5] = fmaf(hbuf[tap][1].y, k1.y, xk[5]);
                    xk[6] = fmaf(hbuf[tap][1].z, k1.z, xk[6]); xk[7] = fmaf(hbuf[tap][1].w, k1.w, xk[7]);
                    xv[0] = fmaf(hbuf[tap][0].x, v0.x, xv[0]); xv[1] = fmaf(hbuf[tap][0].y, v0.y, xv[1]);
                    xv[2] = fmaf(hbuf[tap][0].z, v0.z, xv[2]); xv[3] = fmaf(hbuf[tap][0].w, v0.w, xv[3]);
                    xv[4] = fmaf(hbuf[tap][1].x, v1.x, xv[4]); xv[5] = fmaf(hbuf[tap][1].y, v1.y, xv[5]);
                    xv[6] = fmaf(hbuf[tap][1].z, v1.z, xv[6]); xv[7] = fmaf(hbuf[tap][1].w, v1.w, xv[7]);
                }
            }
        }
        float sk  = ((xk[0]+xk[1]) + (xk[2]+xk[3])) + ((xk[4]+xk[5]) + (xk[6]+xk[7]));
        float ssk = fmaf(xk[0],xk[0], fmaf(xk[1],xk[1], fmaf(xk[2],xk[2], fmaf(xk[3],xk[3],
                    fmaf(xk[4],xk[4], fmaf(xk[5],xk[5], fmaf(xk[6],xk[6], xk[7]*xk[7])))))));
        float sv  = ((xv[0]+xv[1]) + (xv[2]+xv[3])) + ((xv[4]+xv[5]) + (xv[6]+xv[7]));
        float ssv = fmaf(xv[0],xv[0], fmaf(xv[1],xv[1], fmaf(xv[2],xv[2], fmaf(xv[3],xv[3],
                    fmaf(xv[4],xv[4], fmaf(xv[5],xv[5], fmaf(xv[6],xv[6], xv[7]*xv[7])))))));
        red16_2(sk, ssk);
        red16_2(sv, ssv);
        float mk = sk * (1.f/96.f), vark = ssk * (1.f/96.f) - mk*mk;
        float mv = sv * (1.f/96.f), varv = ssv * (1.f/96.f) - mv*mv;
        float rk = rsqrtf(vark + 1e-5f);
        float rv = rsqrtf(varv + 1e-5f);
        if (ACT) {
            ln8_store(xk, mk, rk, gk, betak, c0, ok_);
            ln8_store(xv, mv, rv, gv, betav, c0, ov_);
        }
    }
}

// ---------------------------------------------------------------------------
// Kernel 2: projections as MFMA GEMM. FOUR 16-token tiles per wave (r8).
// ---------------------------------------------------------------------------
__global__ __launch_bounds__(256) void proj_mfma_kernel(
    const short* __restrict__ pq, const short* __restrict__ pk, const short* __restrict__ pv,
    const short* __restrict__ WTq, const short* __restrict__ WTk, const short* __restrict__ WTv,
    const float* __restrict__ bq, const float* __restrict__ bk, const float* __restrict__ bv,
    short* __restrict__ qb, short* __restrict__ kb, short* __restrict__ vt)
{
    int wid  = threadIdx.x >> 6;
    int lane = threadIdx.x & 63;
    int quad = lane >> 4, col = lane & 15;
    int wt = blockIdx.x * 4 + wid;              // 1216 wave-units total

    if (wt < 1008) {                            // ---- q and k: swapped ----
        const short *A, *WT; const float* bias; short* outp;
        int ntokp, row0; float bsc;
        if (wt < 800) { A = pq; WT = WTq; bias = bq; outp = qb; ntokp = NQP; row0 = wt*64; bsc = 1.f; }
        else          { A = pk; WT = WTk; bias = bk; outp = kb; ntokp = NKP; row0 = (wt-800)*64; bsc = KSCL2; }

        short8 bt[4][3];
        #pragma unroll
        for (int ti = 0; ti < 4; ++ti)
            #pragma unroll
            for (int cc = 0; cc < 3; ++cc)
                bt[ti][cc] = ld8(A + (long)(row0 + ti*16 + col)*96 + cc*32 + quad*8);

        int bT[4], tokT[4];
        #pragma unroll
        for (int ti = 0; ti < 4; ++ti) {
            int r = row0 + ti*16;
            bT[ti] = r / ntokp;
            tokT[ti] = (r % ntokp) + col;
        }

        short8 af[2][3];
        #pragma unroll
        for (int cc = 0; cc < 3; ++cc)
            af[0][cc] = ld8(WT + col*96 + cc*32 + quad*8);

        #pragma unroll
        for (int nt = 0; nt < 12; ++nt) {
            if (nt < 11) {
                #pragma unroll
                for (int cc = 0; cc < 3; ++cc)
                    af[(nt+1)&1][cc] = ld8(WT + ((nt+1)*16 + col)*96 + cc*32 + quad*8);
            }
            int o0 = nt*16 + quad*4;            // 4 consecutive outputs
            float4 bo = *reinterpret_cast<const float4*>(bias + o0);
            int h  = (o0 >= 96) ? 1 : 0;
            int d0 = o0 - h*96;
            #pragma unroll
            for (int ti = 0; ti < 4; ++ti) {
                floatx4 acc = {0.f, 0.f, 0.f, 0.f};
                #pragma unroll
                for (int cc = 0; cc < 3; ++cc)
                    acc = MFMA16(af[nt&1][cc], bt[ti][cc], acc);
                shortx4 val;
                val.x = f2s(acc[0] + bo.x*bsc);
                val.y = f2s(acc[1] + bo.y*bsc);
                val.z = f2s(acc[2] + bo.z*bsc);
                val.w = f2s(acc[3] + bo.w*bsc);
                *reinterpret_cast<shortx4*>(outp + ((long)(bT[ti]*2 + h)*ntokp + tokT[ti])*96 + d0) = val;
            }
        }
    } else {                                    // ---- v: original orient ----
        int row0 = (wt - 1008) * 64;
        short8 at[4][3];
        #pragma unroll
        for (int ti = 0; ti < 4; ++ti)
            #pragma unroll
            for (int cc = 0; cc < 3; ++cc)
                at[ti][cc] = ld8(pv + (long)(row0 + ti*16 + col)*96 + cc*32 + quad*8);

        int bT[4], t0T[4];
        #pragma unroll
        for (int ti = 0; ti < 4; ++ti) {
            int r = row0 + ti*16;
            bT[ti] = r / NKP;
            t0T[ti] = (r % NKP) + quad*4;       // 4 consecutive tokens
        }

        short8 bf[2][3];
        #pragma unroll
        for (int cc = 0; cc < 3; ++cc)
            bf[0][cc] = ld8(WTv + col*96 + cc*32 + quad*8);

        #pragma unroll
        for (int nt = 0; nt < 12; ++nt) {
            if (nt < 11) {
                #pragma unroll
                for (int cc = 0; cc < 3; ++cc)
                    bf[(nt+1)&1][cc] = ld8(WTv + ((nt+1)*16 + col)*96 + cc*32 + quad*8);
            }
            int o = nt*16 + col;
            int h = (o >= 96) ? 1 : 0;
            int d = o - h*96;
            float bo = bv[o];
            #pragma unroll
            for (int ti = 0; ti < 4; ++ti) {
                floatx4 acc = {0.f, 0.f, 0.f, 0.f};
                #pragma unroll
                for (int cc = 0; cc < 3; ++cc)
                    acc = MFMA16(at[ti][cc], bf[nt&1][cc], acc);
                shortx4 val;
                val.x = (t0T[ti]+0 < NK) ? f2s(acc[0] + bo) : (short)0;
                val.y = (t0T[ti]+1 < NK) ? f2s(acc[1] + bo) : (short)0;
                val.z = (t0T[ti]+2 < NK) ? f2s(acc[2] + bo) : (short)0;
                val.w = (t0T[ti]+3 < NK) ? f2s(acc[3] + bo) : (short)0;
                *reinterpret_cast<shortx4*>(vt + ((long)(bT[ti]*2 + h)*VROWS + d)*NKPV + t0T[ti]) = val;
            }
        }
    }
}

// ---------------------------------------------------------------------------
// Kernel 3: MFMA attention (r9 version, unchanged — best measured 52 µs).
// ---------------------------------------------------------------------------
__global__ __launch_bounds__(64, 2) void attn_kernel(
    const short* __restrict__ qb, const short* __restrict__ kb,
    const short* __restrict__ vt, const short* __restrict__ relc,
    float* __restrict__ out)
{
    __shared__ __align__(16) short smem[2][16][232];   // 14848 B

    int lane = threadIdx.x & 63;
    int quad = lane >> 4, col = lane & 15;

    int bid = blockIdx.x;                      // 3200 = 8 * 400
    int wt  = (bid & 7) * 400 + (bid >> 3);    // XCD-contiguous ranges (25 waves/bh)
    int bh  = wt / 25;
    int tp  = wt % 25;
    int q0  = tp * 32;                         // rows q0..q0+31

    // Q A-fragments for both tiles
    const short* qrow = qb + ((long)bh*NQP + q0)*96;
    short8 aq[2][3];
    #pragma unroll
    for (int ti = 0; ti < 2; ++ti)
        #pragma unroll
        for (int c = 0; c < 3; ++c)
            aq[ti][c] = ld8(qrow + (ti*16 + col)*96 + c*32 + quad*8);

    // E = Q Rel^T with rel-fragment register double-buffer
    short8 rf[2][3];
    #pragma unroll
    for (int c = 0; c < 3; ++c)
        rf[0][c] = ld8(relc + col*96 + c*32 + quad*8);
    #pragma unroll
    for (int rt = 0; rt < 7; ++rt) {
        if (rt < 6) {
            #pragma unroll
            for (int c = 0; c < 3; ++c)
                rf[(rt+1)&1][c] = ld8(relc + ((rt+1)*16 + col)*96 + c*32 + quad*8);
        }
        #pragma unroll
        for (int ti = 0; ti < 2; ++ti) {
            floatx4 acc = {0.f, 0.f, 0.f, 0.f};
            #pragma unroll
            for (int c = 0; c < 3; ++c)
                acc = MFMA16(aq[ti][c], rf[rt&1][c], acc);
            #pragma unroll
            for (int reg = 0; reg < 4; ++reg)
                smem[ti][quad*4 + reg][rt*16 + col] = f2s(acc[reg]);
        }
    }

    // issue K(0) and K(1) loads now — latency hides under the bias gather
    const short* kbase = kb + (long)bh*NKP*96;
    short8 kf[3][3];
    #pragma unroll
    for (int c = 0; c < 3; ++c)
        kf[0][c] = ld8(kbase + col*96 + c*32 + quad*8);
    #pragma unroll
    for (int c = 0; c < 3; ++c)
        kf[1][c] = ld8(kbase + (16 + col)*96 + c*32 + quad*8);

    // per-row q spatial coords (8 rows per lane: 2 tiles x 4 regs)
    int qyo[2][4], qxo[2][4];
    #pragma unroll
    for (int ti = 0; ti < 2; ++ti)
        #pragma unroll
        for (int reg = 0; reg < 4; ++reg) {
            int qq = q0 + ti*16 + quad*4 + reg;
            int jj = (qq > 0) ? (qq - 1) : 0;
            qyo[ti][reg] = jj / QW;
            qxo[ti][reg] = jj % QW;
        }

    // hoisted rel-bias gather: 13 kt x 8 rows -> 52 packed-f16 regs
    unsigned bpk[2][13][2];
    #pragma unroll
    for (int kt = 0; kt < 13; ++kt) {
        int k  = kt*16 + col;
        int kk = (k > 0) ? (k - 1) : 0;
        int ky = kk / 14;  ky = (ky < 13) ? ky : 13;
        int kx = kk - 14*ky;
        int oh  = 26 - 2*ky;
        int ow2 = 26 - 2*kx;
        #pragma unroll
        for (int ti = 0; ti < 2; ++ti) {
            float bs[4];
            #pragma unroll
            for (int reg = 0; reg < 4; ++reg) {
                const short* er = &smem[ti][quad*4 + reg][0];
                float bias = s2f(er[qyo[ti][reg] + oh]) + s2f(er[54 + qxo[ti][reg] + ow2]);
                if (kt == 0) bias = (col == 0) ? 0.f : bias;                        // CLS col
                if (q0 == 0 && ti == 0 && reg == 0) bias = (quad == 0) ? 0.f : bias; // CLS row
                bs[reg] = bias;
            }
            bpk[ti][kt][0] = pkhf(bs[0], bs[1]);
            bpk[ti][kt][1] = pkhf(bs[2], bs[3]);
        }
    }

    // fused S2 = log2e*(Q K^T + rel bias); P = exp2(S2) -> overwrites E.
    // K dist-2 register ring; V(0) prefetch issued at kt==11.
    const short* vbase = vt + (long)bh*VROWS*NKPV;
    short8 vf[2][7];
    #pragma unroll
    for (int kt = 0; kt < 13; ++kt) {
        if (kt < 11) {
            #pragma unroll
            for (int c = 0; c < 3; ++c)
                kf[(kt+2)%3][c] = ld8(kbase + ((kt+2)*16 + col)*96 + c*32 + quad*8);
        } else if (kt == 11) {
            #pragma unroll
            for (int nt = 0; nt < 7; ++nt)
                vf[0][nt] = ld8(vbase + (nt*16 + col)*NKPV + quad*8);
        }
        int k = kt*16 + col;
        __builtin_amdgcn_s_setprio(1);
        floatx4 accA = {0.f, 0.f, 0.f, 0.f};
        floatx4 accB = {0.f, 0.f, 0.f, 0.f};
        #pragma unroll
        for (int c = 0; c < 3; ++c) {
            accA = MFMA16(aq[0][c], kf[kt%3][c], accA);
            accB = MFMA16(aq[1][c], kf[kt%3][c], accB);
        }
        __builtin_amdgcn_s_setprio(0);
        unsigned a0 = bpk[0][kt][0], a1 = bpk[0][kt][1];
        unsigned b0 = bpk[1][kt][0], b1 = bpk[1][kt][1];
        smem[0][quad*4 + 0][k] = f2s(__builtin_amdgcn_exp2f(accA[0] + hflo(a0)));
        smem[0][quad*4 + 1][k] = f2s(__builtin_amdgcn_exp2f(accA[1] + hfhi(a0)));
        smem[0][quad*4 + 2][k] = f2s(__builtin_amdgcn_exp2f(accA[2] + hflo(a1)));
        smem[0][quad*4 + 3][k] = f2s(__builtin_amdgcn_exp2f(accA[3] + hfhi(a1)));
        smem[1][quad*4 + 0][k] = f2s(__builtin_amdgcn_exp2f(accB[0] + hflo(b0)));
        smem[1][quad*4 + 1][k] = f2s(__builtin_amdgcn_exp2f(accB[1] + hfhi(b0)));
        smem[1][quad*4 + 2][k] = f2s(__builtin_amdgcn_exp2f(accB[2] + hflo(b1)));
        smem[1][quad*4 + 3][k] = f2s(__builtin_amdgcn_exp2f(accB[3] + hfhi(b1)));
    }
    #pragma unroll
    for (int ti = 0; ti < 2; ++ti)             // zero PV pad cols 208..223
        #pragma unroll
        for (int reg = 0; reg < 4; ++reg)
            smem[ti][quad*4 + reg][208 + col] = 0;

    // O = P V (7 K-chunks of 32; 6 V n-tiles + ones-row n-tile = row sums)
    floatx4 o[2][7];
    #pragma unroll
    for (int ti = 0; ti < 2; ++ti)
        #pragma unroll
        for (int nt = 0; nt < 7; ++nt) o[ti][nt] = floatx4{0.f, 0.f, 0.f, 0.f};
    #pragma unroll
    for (int c = 0; c < 7; ++c) {
        if (c < 6) {
            #pragma unroll
            for (int nt = 0; nt < 7; ++nt)
                vf[(c+1)&1][nt] = ld8(vbase + (nt*16 + col)*NKPV + (c+1)*32 + quad*8);
        }
        short8 apA = ld8(&smem[0][col][c*32 + quad*8]);
        short8 apB = ld8(&smem[1][col][c*32 + quad*8]);
        __builtin_amdgcn_s_setprio(1);
        #pragma unroll
        for (int nt = 0; nt < 7; ++nt) {
            o[0][nt] = MFMA16(apA, vf[c&1][nt], o[0][nt]);
            o[1][nt] = MFMA16(apB, vf[c&1][nt], o[1][nt]);
        }
        __builtin_amdgcn_s_setprio(0);
    }

    // broadcast row sums
    float inv[2][4];
    #pragma unroll
    for (int ti = 0; ti < 2; ++ti)
        #pragma unroll
        for (int reg = 0; reg < 4; ++reg) {
            float srow = __shfl(o[ti][6][reg], lane & 48, 64);
            inv[ti][reg] = 1.0f / srow;
        }

    // epilogue: stage o*inv into dead P-LDS as f32 [2][16][stride 102],
    // then 2 lanes per row emit 48 contiguous channels (vectorized I/O).
    float* fsm = reinterpret_cast<float*>(&smem[0][0][0]);
    #pragma unroll
    for (int ti = 0; ti < 2; ++ti)
        #pragma unroll
        for (int nt = 0; nt < 6; ++nt)
            #pragma unroll
            for (int reg = 0; reg < 4; ++reg)
                fsm[(ti*16 + quad*4 + reg)*102 + nt*16 + col] = o[ti][nt][reg] * inv[ti][reg];

    int b = bh >> 1, h = bh & 1;
    int r2  = lane >> 1;                       // 0..31: row across both tiles
    int h2  = lane & 1;                        // half-row
    int ti2 = r2 >> 4, row2 = r2 & 15;
    int q   = q0 + ti2*16 + row2;
    int ch0 = h2 * 48;
    if (q < NQ) {
        const float* src  = fsm + (ti2*16 + row2)*102 + ch0;
        const short* resp = qb + ((long)bh*NQP + q)*96 + ch0;
        float*       outp = out + ((long)b*NQ + q)*192 + h*96 + ch0;
        #pragma unroll
        for (int i = 0; i < 6; ++i) {
            float2 v0 = *reinterpret_cast<const float2*>(src + i*8 + 0);
            float2 v1 = *reinterpret_cast<const float2*>(src + i*8 + 2);
            float2 v2 = *reinterpret_cast<const float2*>(src + i*8 + 4);
            float2 v3 = *reinterpret_cast<const float2*>(src + i*8 + 6);
            float r_[8];
            if (q > 0) {
                short8 rs = ld8(resp + i*8);
                #pragma unroll
                for (int j = 0; j < 8; ++j) r_[j] = s2f(rs[j]);
            } else {
                #pragma unroll
                for (int j = 0; j < 8; ++j) r_[j] = 0.f;
            }
            float4 o0, o1;
            o0.x = v0.x + r_[0]; o0.y = v0.y + r_[1];
            o0.z = v1.x + r_[2]; o0.w = v1.y + r_[3];
            o1.x = v2.x + r_[4]; o1.y = v2.y + r_[5];
            o1.z = v3.x + r_[6]; o1.w = v3.y + r_[7];
            *reinterpret_cast<float4*>(outp + i*8)     = o0;
            *reinterpret_cast<float4*>(outp + i*8 + 4) = o1;
        }
    }
}

// ---------------------------------------------------------------------------
extern "C" void kernel_launch(void* const* d_in, const int* in_sizes, int n_in,
                              void* d_out, int out_size, void* d_ws, size_t ws_size,
                              hipStream_t stream)
{
    const float* hs    = (const float*)d_in[0];
    const float* Wq    = (const float*)d_in[1];
    const float* bq    = (const float*)d_in[2];
    const float* Wk    = (const float*)d_in[3];
    const float* bk    = (const float*)d_in[4];
    const float* Wv    = (const float*)d_in[5];
    const float* bv    = (const float*)d_in[6];
    const float* pqw   = (const float*)d_in[7];
    const float* pkw   = (const float*)d_in[8];
    const float* pvw   = (const float*)d_in[9];
    const float* gq    = (const float*)d_in[10];
    const float* betaq = (const float*)d_in[11];
    const float* gk    = (const float*)d_in[12];
    const float* betak = (const float*)d_in[13];
    const float* gv    = (const float*)d_in[14];
    const float* betav = (const float*)d_in[15];
    const float* relh  = (const float*)d_in[16];
    const float* relw  = (const float*)d_in[17];
    float* out = (float*)d_out;

    // workspace carve (bf16 as short) — ~46.3 MB
    short* pq   = (short*)d_ws;                  // [64][800][96]
    short* pk   = pq  + (long)B_*NQP*CIN;        // [64][208][96]
    short* pv   = pk  + (long)B_*NKP*CIN;        // [64][208][96]
    short* qb   = pv  + (long)B_*NKP*CIN;        // [128][800][96]
    short* kb   = qb  + (long)128*NQP*96;        // [128][208][96]
    short* vt   = kb  + (long)128*NKP*96;        // [128][112][224]
    short* WTq  = vt  + (long)128*VROWS*NKPV;    // [192][96]
    short* WTk  = WTq + 192*96;
    short* WTv  = WTk + 192*96;
    short* relc = WTv + 192*96;                  // [112][96]
    float* cwqT = (float*)(relc + 112*96);       // [9][96] fp32
    float* cwkT = cwqT + 9*96;
    float* cwvT = cwkT + 9*96;

    prep_w_kernel<<<11, 256, 0, stream>>>(pqw, pkw, pvw, cwqT, cwkT, cwvT);

    pool_ln_kernel<<<4032 + 578, 256, 0, stream>>>(
        hs, cwqT, cwkT, cwvT, gq, betaq, gk, betak, gv, betav, pq, pk, pv,
        Wq, Wk, Wv, relh, relw, WTq, WTk, WTv, relc, vt);

    proj_mfma_kernel<<<1216/4, 256, 0, stream>>>(
        pq, pk, pv, WTq, WTk, WTv, bq, bk, bv, qb, kb, vt);

    attn_kernel<<<3200, 64, 0, stream>>>(qb, kb, vt, relc, out);
}